// Round 13
// baseline (203.752 us; speedup 1.0000x reference)
//
#include <hip/hip_runtime.h>
#include <hip/hip_bf16.h>

// RoPEAttention B=2 S=2048 D=1024 H=16 HD=64, fp32 in/out.
// R22: flash -> ONE barrier per tile via R20-ordering double-buffer:
//      compute t from buf[cur] FIRST, then commit regs(t+1) -> buf[cur^1],
//      issue t+2 loads, lgkmcnt(0)+s_barrier. (R17 failed with commit/load
//      BEFORE compute: VGPR 156, -13%. R20/R21 ordering validated twice.)
//      Hazard: barrier at end of iter t-1 guarantees buf[cur^1] readers done,
//      so writing it during compute-t is safe. Global t+2 loads cross the
//      barrier un-drained (vmcnt untouched; precise reg deps at commit).
// R21: gemm_out reg-staged dbuf (byte-identical). R20: gemm_qkv reg-staged
//      dbuf (byte-identical). R16: flash Q-block 256 core (kept).
// ws (shorts): qbh[0,4M) kbh[4M,8M) vt[8M,12M) xb[16M,20M)
//              wqkvb[20M,23M) wob[23M,24M) po[24M,32M) pl(fp32) after.

#define B_ 2
#define S_ 2048
#define D_ 1024
#define H_ 16
#define HD_ 64
#define M_ (B_*S_)
#define SPLIT_ 2
#define KSPAN_ (S_/SPLIT_)    // 1024 keys per split

typedef __attribute__((ext_vector_type(8))) short short8;
typedef __attribute__((ext_vector_type(4))) short short4v;
typedef __attribute__((ext_vector_type(4))) float f32x4;
typedef __attribute__((ext_vector_type(4))) _Float16 half4;
typedef __attribute__((ext_vector_type(8))) _Float16 half8;

static __device__ __forceinline__ short f2bf(float f) {
    __hip_bfloat16 h = __float2bfloat16(f);
    return *reinterpret_cast<short*>(&h);
}
static __device__ __forceinline__ short f2h(float f) {
    _Float16 h = (_Float16)f;
    return *reinterpret_cast<short*>(&h);
}

typedef __attribute__((address_space(1))) const unsigned int gu32_t;
typedef __attribute__((address_space(3))) unsigned int lu32_t;
static __device__ __forceinline__ void gld16(const short* g, short* l) {
    __builtin_amdgcn_global_load_lds((gu32_t*)g, (lu32_t*)l, 16, 0, 0);
}

// ---------------- fp32 -> bf16 convert: x, wq|wk|wv (concat), wo ----------------
__global__ __launch_bounds__(256)
void convert_bf16(const float* __restrict__ x,
                  const float* __restrict__ wq, const float* __restrict__ wk,
                  const float* __restrict__ wv, const float* __restrict__ wo,
                  short* __restrict__ xb, short* __restrict__ wqkvb, short* __restrict__ wob)
{
    const size_t t4 = ((size_t)blockIdx.x * 256 + threadIdx.x) * 4;
    const float* src; short* dst; size_t off, doff;
    if (t4 < 4194304)      { src = x;  dst = xb;    off = t4;           doff = t4; }
    else if (t4 < 5242880) { src = wq; dst = wqkvb; off = t4 - 4194304; doff = t4 - 4194304; }
    else if (t4 < 6291456) { src = wk; dst = wqkvb; off = t4 - 5242880; doff = t4 - 4194304; }
    else if (t4 < 7340032) { src = wv; dst = wqkvb; off = t4 - 6291456; doff = t4 - 4194304; }
    else                   { src = wo; dst = wob;   off = t4 - 7340032; doff = t4 - 7340032; }
    float4 v = *(const float4*)(src + off);
    short4v s = { f2bf(v.x), f2bf(v.y), f2bf(v.z), f2bf(v.w) };
    *(short4v*)(dst + doff) = s;
}

// ---------------- bf16 MFMA GEMM NT 128x128, BK=64 XOR-swizzled, reg-staged dbuf ----------------
// Epilogue: which==0/1 -> fused RMSNorm+RoPE -> Qb/Kb bf16 [B,H,S,HD]
//           which==2   -> Vt f16 [B,H,HD,S]
__global__ __launch_bounds__(256)
void gemm_qkv(const short* __restrict__ A, const short* __restrict__ Bw,
              short* __restrict__ Qb, short* __restrict__ Kb, short* __restrict__ Vt,
              const float* __restrict__ q_scale, const float* __restrict__ k_scale,
              const float* __restrict__ rope_cos, const float* __restrict__ rope_sin)
{
    __shared__ __align__(16) short As[2][128*64];   // 2 x 16KB
    __shared__ __align__(16) short Bs[2][128*64];   // 2 x 16KB  (total 64KB)
    const int tid = threadIdx.x;
    const int w = tid >> 6, lane = tid & 63, quad = lane >> 4, l16 = lane & 15;
    const int wr = w >> 1, wc = w & 1;
    const int bm0 = blockIdx.x * 128, bn0 = blockIdx.y * 128;

    const int row_ = tid >> 3;
    const int kslot = tid & 7;
    const short* gA[4]; const short* gB[4];
    int wo_[4];
    #pragma unroll
    for (int j = 0; j < 4; ++j) {
        const int row = j*32 + row_;
        const int kch = kslot ^ (row & 7);
        gA[j] = A  + (size_t)(bm0 + row) * 1024 + kch*8;
        gB[j] = Bw + (size_t)(bn0 + row) * 1024 + kch*8;
        wo_[j] = row*64 + kslot*8;       // == j*2048 + w*512 + lane*8
    }

    f32x4 acc[4][4];
    #pragma unroll
    for (int i = 0; i < 4; ++i)
        #pragma unroll
        for (int j = 0; j < 4; ++j) acc[i][j] = (f32x4){0.f,0.f,0.f,0.f};

    // prologue: tile0 -> regs -> buf0; tile1 -> regs; barrier
    short8 rA[4], rB[4];
    #pragma unroll
    for (int j = 0; j < 4; ++j) { rA[j] = *(const short8*)gA[j]; rB[j] = *(const short8*)gB[j]; }
    #pragma unroll
    for (int j = 0; j < 4; ++j) {
        *(short8*)(&As[0][wo_[j]]) = rA[j];
        *(short8*)(&Bs[0][wo_[j]]) = rB[j];
    }
    #pragma unroll
    for (int j = 0; j < 4; ++j) { rA[j] = *(const short8*)(gA[j] + 64); rB[j] = *(const short8*)(gB[j] + 64); }
    asm volatile("s_waitcnt lgkmcnt(0)" ::: "memory");
    __builtin_amdgcn_s_barrier();
    __builtin_amdgcn_sched_barrier(0);

    int cur = 0;
    for (int t = 0; t < 16; ++t) {
        // compute tile t from buf[cur]
        short8 af[2][4], bfr[2][4];
        #pragma unroll
        for (int ph = 0; ph < 2; ++ph)
            #pragma unroll
            for (int i = 0; i < 4; ++i) {
                const int ra = wr*64 + i*16 + l16;
                af[ph][i]  = *(const short8*)(&As[cur][ra*64 + (((ph*4 + quad) ^ (ra & 7)) << 3)]);
                const int rb = wc*64 + i*16 + l16;
                bfr[ph][i] = *(const short8*)(&Bs[cur][rb*64 + (((ph*4 + quad) ^ (rb & 7)) << 3)]);
            }
        #pragma unroll
        for (int ph = 0; ph < 2; ++ph)
            #pragma unroll
            for (int i = 0; i < 4; ++i)
                #pragma unroll
                for (int j = 0; j < 4; ++j)
                    acc[i][j] = __builtin_amdgcn_mfma_f32_16x16x32_bf16(af[ph][i], bfr[ph][j], acc[i][j], 0, 0, 0);

        if (t < 15) {
            // commit tile t+1 (in regs since last iter) to the other buffer
            #pragma unroll
            for (int j = 0; j < 4; ++j) {
                *(short8*)(&As[cur ^ 1][wo_[j]]) = rA[j];
                *(short8*)(&Bs[cur ^ 1][wo_[j]]) = rB[j];
            }
            // issue tile t+2 loads (stay in flight across the barrier: no vmcnt drain)
            if (t < 14) {
                const int k0 = (t + 2) * 64;
                #pragma unroll
                for (int j = 0; j < 4; ++j) {
                    rA[j] = *(const short8*)(gA[j] + k0);
                    rB[j] = *(const short8*)(gB[j] + k0);
                }
            }
            asm volatile("s_waitcnt lgkmcnt(0)" ::: "memory");
            __builtin_amdgcn_s_barrier();
            __builtin_amdgcn_sched_barrier(0);
            cur ^= 1;
        }
    }

    const int nbase = bn0 + wc*64;
    const int which = nbase >> 10;
    const int h     = (nbase & 1023) >> 6;

    if (which < 2) {
        const float* sc = which ? k_scale : q_scale;
        short* dst      = which ? Kb : Qb;
        const float fold = which ? 1.0f : 0.18033688011112042f;  // q: (1/8)*log2(e)
        float scv[4];
        #pragma unroll
        for (int j = 0; j < 4; ++j) scv[j] = sc[j*16 + l16];
        #pragma unroll
        for (int i = 0; i < 4; ++i) {
            #pragma unroll
            for (int r = 0; r < 4; ++r) {
                const int m = bm0 + wr*64 + i*16 + quad*4 + r;
                const int b = m >> 11, s = m & (S_-1);
                float ss = 0.f;
                #pragma unroll
                for (int j = 0; j < 4; ++j) ss += acc[i][j][r] * acc[i][j][r];
                #pragma unroll
                for (int msk = 1; msk <= 8; msk <<= 1) ss += __shfl_xor(ss, msk, 64);
                const float rn = rsqrtf(ss * (1.0f/64.0f) + 1e-6f);
                #pragma unroll
                for (int j = 0; j < 4; ++j) {
                    const int hd = j*16 + l16;
                    const float nv = acc[i][j][r] * rn * scv[j];
                    const float c  = rope_cos[s*32 + (hd >> 1)];
                    const float sn = rope_sin[s*32 + (hd >> 1)];
                    const float partner = __shfl_xor(nv, 1, 64);
                    const float o = (hd & 1) ? (partner * sn + nv * c) : (nv * c - partner * sn);
                    dst[(((size_t)b*H_ + h)*S_ + s)*HD_ + hd] = f2bf(o * fold);
                }
            }
        }
    } else {
        #pragma unroll
        for (int i = 0; i < 4; ++i)
            #pragma unroll
            for (int r = 0; r < 4; ++r) {
                const int m = bm0 + wr*64 + i*16 + quad*4 + r;
                const int b = m >> 11, s = m & (S_-1);
                #pragma unroll
                for (int j = 0; j < 4; ++j) {
                    const int hd = j*16 + l16;
                    Vt[(((size_t)b*H_ + h)*HD_ + hd)*S_ + s] = f2h(acc[i][j][r]);
                }
            }
    }
}

// ---------------- out-proj GEMM 64x128, BK=64 XOR-swizzled, reg-staged dbuf ----------------
__global__ __launch_bounds__(256)
void gemm_out(const short* __restrict__ po, const float* __restrict__ pl,
              const short* __restrict__ Bw, float* __restrict__ C)
{
    __shared__ __align__(16) short As[2][64*64];    // 2 x 8KB
    __shared__ __align__(16) short Bs[2][128*64];   // 2 x 16KB (total 48KB)
    const int tid = threadIdx.x;
    const int w = tid >> 6, lane = tid & 63, quad = lane >> 4, l16 = lane & 15;
    const int bm0 = blockIdx.x * 64, bn0 = blockIdx.y * 128;

    // B reg-staging (same slot math as gemm_qkv)
    const int row_ = tid >> 3;
    const int kslot = tid & 7;
    const short* gB[4];
    int woB[4];
    #pragma unroll
    for (int j = 0; j < 4; ++j) {
        const int row = j*32 + row_;
        const int kch = kslot ^ (row & 7);
        gB[j] = Bw + (size_t)(bn0 + row) * 1024 + kch*8;
        woB[j] = row*64 + kslot*8;
    }

    // A production: thread -> row srow, chunks ch0, ch0+1 (8 shorts each)
    const int srow = tid >> 2;          // 0..63
    const int ch0  = (tid & 3) * 2;     // 0,2,4,6
    const int m = bm0 + srow;
    const int b = m >> 11, s = m & (S_-1);
    const short* p0 = po +            (size_t)m * 1024;
    const short* p1 = po + 4194304 + (size_t)m * 1024;

    float inv[16];
    #pragma unroll
    for (int h = 0; h < 16; ++h)
        inv[h] = 1.0f / (pl[((size_t)(b*16 + h))*S_ + s] + pl[65536 + ((size_t)(b*16 + h))*S_ + s]);

    f32x4 acc[4][2];
    #pragma unroll
    for (int i = 0; i < 4; ++i) {
        acc[i][0] = (f32x4){0.f,0.f,0.f,0.f};
        acc[i][1] = (f32x4){0.f,0.f,0.f,0.f};
    }

    // ---- prologue: tile0 -> regs -> buf0; tile1 -> regs; barrier ----
    short8 rB[4];
    half8 d00, d01, d10, d11;
    #pragma unroll
    for (int j = 0; j < 4; ++j) rB[j] = *(const short8*)gB[j];
    d00 = *(const half8*)(p0 + ch0*8);
    d01 = *(const half8*)(p1 + ch0*8);
    d10 = *(const half8*)(p0 + ch0*8 + 8);
    d11 = *(const half8*)(p1 + ch0*8 + 8);
    {
        const float invh = inv[0];
        short8 a0, a1;
        #pragma unroll
        for (int j = 0; j < 8; ++j) {
            a0[j] = f2bf(((float)d00[j] + (float)d01[j]) * invh);
            a1[j] = f2bf(((float)d10[j] + (float)d11[j]) * invh);
        }
        *(short8*)(&As[0][srow*64 + (((ch0    ) ^ (srow & 7)) << 3)]) = a0;
        *(short8*)(&As[0][srow*64 + (((ch0 + 1) ^ (srow & 7)) << 3)]) = a1;
        #pragma unroll
        for (int j = 0; j < 4; ++j)
            *(short8*)(&Bs[0][woB[j]]) = rB[j];
    }
    #pragma unroll
    for (int j = 0; j < 4; ++j) rB[j] = *(const short8*)(gB[j] + 64);
    d00 = *(const half8*)(p0 + 64 + ch0*8);
    d01 = *(const half8*)(p1 + 64 + ch0*8);
    d10 = *(const half8*)(p0 + 64 + ch0*8 + 8);
    d11 = *(const half8*)(p1 + 64 + ch0*8 + 8);
    asm volatile("s_waitcnt lgkmcnt(0)" ::: "memory");
    __builtin_amdgcn_s_barrier();
    __builtin_amdgcn_sched_barrier(0);

    int cur = 0;
    for (int t = 0; t < 16; ++t) {
        // compute tile t from buf[cur]
        #pragma unroll
        for (int ph = 0; ph < 2; ++ph) {
            short8 af[4], bfr[2];
            #pragma unroll
            for (int i = 0; i < 4; ++i) {
                const int ra = i*16 + l16;
                af[i] = *(const short8*)(&As[cur][ra*64 + (((ph*4 + quad) ^ (ra & 7)) << 3)]);
            }
            #pragma unroll
            for (int j = 0; j < 2; ++j) {
                const int rb = w*32 + j*16 + l16;
                bfr[j] = *(const short8*)(&Bs[cur][rb*64 + (((ph*4 + quad) ^ (rb & 7)) << 3)]);
            }
            #pragma unroll
            for (int i = 0; i < 4; ++i)
                #pragma unroll
                for (int j = 0; j < 2; ++j)
                    acc[i][j] = __builtin_amdgcn_mfma_f32_16x16x32_bf16(af[i], bfr[j], acc[i][j], 0, 0, 0);
        }

        if (t < 15) {
            // commit tile t+1 (regs) to the other buffer
            const float invh = inv[t + 1];
            short8 a0, a1;
            #pragma unroll
            for (int j = 0; j < 8; ++j) {
                a0[j] = f2bf(((float)d00[j] + (float)d01[j]) * invh);
                a1[j] = f2bf(((float)d10[j] + (float)d11[j]) * invh);
            }
            *(short8*)(&As[cur ^ 1][srow*64 + (((ch0    ) ^ (srow & 7)) << 3)]) = a0;
            *(short8*)(&As[cur ^ 1][srow*64 + (((ch0 + 1) ^ (srow & 7)) << 3)]) = a1;
            #pragma unroll
            for (int j = 0; j < 4; ++j)
                *(short8*)(&Bs[cur ^ 1][woB[j]]) = rB[j];
            // issue tile t+2 loads (no vmcnt drain; stay in flight across barrier)
            if (t < 14) {
                const int k0 = (t + 2) * 64;
                #pragma unroll
                for (int j = 0; j < 4; ++j) rB[j] = *(const short8*)(gB[j] + k0);
                d00 = *(const half8*)(p0 + k0 + ch0*8);
                d01 = *(const half8*)(p1 + k0 + ch0*8);
                d10 = *(const half8*)(p0 + k0 + ch0*8 + 8);
                d11 = *(const half8*)(p1 + k0 + ch0*8 + 8);
            }
            asm volatile("s_waitcnt lgkmcnt(0)" ::: "memory");
            __builtin_amdgcn_s_barrier();
            __builtin_amdgcn_sched_barrier(0);
            cur ^= 1;
        }
    }

    #pragma unroll
    for (int i = 0; i < 4; ++i)
        #pragma unroll
        for (int r = 0; r < 4; ++r) {
            const int mm = bm0 + i*16 + quad*4 + r;
            #pragma unroll
            for (int j = 0; j < 2; ++j) {
                const int n = bn0 + w*32 + j*16 + l16;
                C[(size_t)mm*1024 + n] = acc[i][j][r];
            }
        }
}

// ---------------- MFMA flash attention partial, split-K=2, XCD-swizzled, Q256, 1-barrier dbuf ----------------
__global__ __launch_bounds__(256)
void flash_mfma(const short* __restrict__ qb, const short* __restrict__ kb,
                const short* __restrict__ vt, short* __restrict__ po, float* __restrict__ pl)
{
    __shared__ __align__(16) short Ks[2][64*64];   // 2 x 8KB
    __shared__ __align__(16) short Vs[2][64*64];   // 2 x 8KB (f16 bits, [d][key] swizzled)

    const int id   = blockIdx.x;
    const int xcd  = id & 7;
    const int rest = id >> 3;
    const int qblk = rest & 7;                // 8 q-blocks of 256
    const int g    = (rest >> 3) * 8 + xcd;   // (bh,sp) group 0..63
    const int bh   = g >> 1;
    const int sp   = g & 1;

    const int tid  = threadIdx.x;
    const int wv   = tid >> 6;
    const int lane = tid & 63;
    const int quad = lane >> 4;
    const int l16  = lane & 15;
    const int b    = bh >> 4, h = bh & (H_-1);
    const int q0   = qblk * 256 + wv * 64;    // 64 q-rows per wave
    const int kt0  = sp * KSPAN_;
    const size_t hbase = (size_t)bh * S_ * HD_;
    const size_t vbase = (size_t)bh * HD_ * S_;
    short* po_sp = po + (size_t)sp * 4194304;
    float* pl_sp = pl + (size_t)sp * 65536;

    const int c0r = tid >> 3,       c0c = tid & 7;
    const int c1r = (tid+256) >> 3, c1c = (tid+256) & 7;
    const int w0 = c0r*64 + ((c0c ^ (c0r & 7)) << 3);
    const int w1 = c1r*64 + ((c1c ^ (c1r & 7)) << 3);

    short8 qfrag[4][2];
    #pragma unroll
    for (int qf = 0; qf < 4; ++qf)
        #pragma unroll
        for (int c = 0; c < 2; ++c)
            qfrag[qf][c] = *(const short8*)(qb + hbase + (size_t)(q0 + qf*16 + l16)*HD_ + c*32 + quad*8);

    f32x4 Oacc[4][4];
    #pragma unroll
    for (int qf = 0; qf < 4; ++qf)
        #pragma unroll
        for (int dt = 0; dt < 4; ++dt) Oacc[qf][dt] = (f32x4){0.f,0.f,0.f,0.f};
    float l_lane[4] = {0.f, 0.f, 0.f, 0.f};

    const int NT = KSPAN_/64;   // 16

    // prologue: tile0 -> regs -> buf0; tile1 -> regs; barrier
    short8 rk0 = *(const short8*)(kb + hbase + (size_t)(kt0 + c0r)*HD_ + c0c*8);
    short8 rk1 = *(const short8*)(kb + hbase + (size_t)(kt0 + c1r)*HD_ + c1c*8);
    short8 rv0 = *(const short8*)(vt + vbase + (size_t)c0r*S_ + kt0 + c0c*8);
    short8 rv1 = *(const short8*)(vt + vbase + (size_t)c1r*S_ + kt0 + c1c*8);
    *(short8*)(&Ks[0][w0]) = rk0;
    *(short8*)(&Ks[0][w1]) = rk1;
    *(short8*)(&Vs[0][w0]) = rv0;
    *(short8*)(&Vs[0][w1]) = rv1;
    {
        const int ktn = kt0 + 64;
        rk0 = *(const short8*)(kb + hbase + (size_t)(ktn + c0r)*HD_ + c0c*8);
        rk1 = *(const short8*)(kb + hbase + (size_t)(ktn + c1r)*HD_ + c1c*8);
        rv0 = *(const short8*)(vt + vbase + (size_t)c0r*S_ + ktn + c0c*8);
        rv1 = *(const short8*)(vt + vbase + (size_t)c1r*S_ + ktn + c1c*8);
    }
    asm volatile("s_waitcnt lgkmcnt(0)" ::: "memory");
    __builtin_amdgcn_s_barrier();
    __builtin_amdgcn_sched_barrier(0);

    int cur = 0;
    #pragma unroll 1
    for (int t = 0; t < NT; ++t) {
        // compute tile t from buf[cur]
        #pragma unroll
        for (int st = 0; st < 4; ++st) {
            short8 kf0 = *(const short8*)(&Ks[cur][(st*16 + l16)*64 + (((quad    ) ^ (l16 & 7)) << 3)]);
            short8 kf1 = *(const short8*)(&Ks[cur][(st*16 + l16)*64 + (((4 + quad) ^ (l16 & 7)) << 3)]);
            const int ch16 = st*2 + (quad >> 1);
            const int sw   = ((ch16 ^ (l16 & 7)) << 3) + (quad & 1)*4;
            half4 va[4];
            #pragma unroll
            for (int dt = 0; dt < 4; ++dt)
                va[dt] = *(const half4*)(&Vs[cur][(dt*16 + l16)*64 + sw]);
            #pragma unroll
            for (int qf = 0; qf < 4; ++qf) {
                f32x4 acc = (f32x4){0.f,0.f,0.f,0.f};
                acc = __builtin_amdgcn_mfma_f32_16x16x32_bf16(kf0, qfrag[qf][0], acc, 0, 0, 0);
                acc = __builtin_amdgcn_mfma_f32_16x16x32_bf16(kf1, qfrag[qf][1], acc, 0, 0, 0);
                half4 pb;
                #pragma unroll
                for (int r = 0; r < 4; ++r) {
                    float p = __builtin_amdgcn_exp2f(acc[r] - 12.0f);
                    l_lane[qf] += p;
                    pb[r] = (_Float16)p;
                }
                #pragma unroll
                for (int dt = 0; dt < 4; ++dt)
                    Oacc[qf][dt] = __builtin_amdgcn_mfma_f32_16x16x16f16(va[dt], pb, Oacc[qf][dt], 0, 0, 0);
            }
        }

        if (t < NT - 1) {
            // commit tile t+1 (regs) to the other buffer
            *(short8*)(&Ks[cur ^ 1][w0]) = rk0;
            *(short8*)(&Ks[cur ^ 1][w1]) = rk1;
            *(short8*)(&Vs[cur ^ 1][w0]) = rv0;
            *(short8*)(&Vs[cur ^ 1][w1]) = rv1;
            // issue tile t+2 loads (no vmcnt drain; stay in flight across barrier)
            if (t < NT - 2) {
                const int ktn = kt0 + (t+2)*64;
                rk0 = *(const short8*)(kb + hbase + (size_t)(ktn + c0r)*HD_ + c0c*8);
                rk1 = *(const short8*)(kb + hbase + (size_t)(ktn + c1r)*HD_ + c1c*8);
                rv0 = *(const short8*)(vt + vbase + (size_t)c0r*S_ + ktn + c0c*8);
                rv1 = *(const short8*)(vt + vbase + (size_t)c1r*S_ + ktn + c1c*8);
            }
            asm volatile("s_waitcnt lgkmcnt(0)" ::: "memory");
            __builtin_amdgcn_s_barrier();
            __builtin_amdgcn_sched_barrier(0);
            cur ^= 1;
        }
    }

    #pragma unroll
    for (int qf = 0; qf < 4; ++qf) {
        l_lane[qf] += __shfl_xor(l_lane[qf], 16, 64);
        l_lane[qf] += __shfl_xor(l_lane[qf], 32, 64);
        if (quad == 0) pl_sp[(size_t)bh*S_ + q0 + qf*16 + l16] = l_lane[qf];
    }
    #pragma unroll
    for (int qf = 0; qf < 4; ++qf) {
        const int s = q0 + qf*16 + l16;
        #pragma unroll
        for (int dt = 0; dt < 4; ++dt) {
            short4v o;
            #pragma unroll
            for (int r = 0; r < 4; ++r) o[r] = f2h(Oacc[qf][dt][r]);
            *(short4v*)(po_sp + (((size_t)b*S_ + s)*H_ + h)*HD_ + dt*16 + quad*4) = o;
        }
    }
}

extern "C" void kernel_launch(void* const* d_in, const int* in_sizes, int n_in,
                              void* d_out, int out_size, void* d_ws, size_t ws_size,
                              hipStream_t stream)
{
    (void)in_sizes; (void)n_in; (void)out_size; (void)ws_size;
    const float* x        = (const float*)d_in[0];
    const float* wq       = (const float*)d_in[1];
    const float* wk       = (const float*)d_in[2];
    const float* wv       = (const float*)d_in[3];
    const float* wo       = (const float*)d_in[4];
    const float* q_scale  = (const float*)d_in[5];
    const float* k_scale  = (const float*)d_in[6];
    const float* rope_cos = (const float*)d_in[7];
    const float* rope_sin = (const float*)d_in[8];
    float* out = (float*)d_out;
    short* ws  = (short*)d_ws;

    short* qbh   = ws;                 // 4M shorts
    short* kbh   = ws + 4194304;
    short* vt    = ws + 8388608;
    short* xb    = ws + 16777216;
    short* wqkvb = ws + 20971520;      // 3M shorts
    short* wob   = ws + 24117248;      // 1M shorts
    short* po    = ws + 25165824;      // 2 x 4M shorts (f16)
    float* pl    = (float*)(ws + 33554432);  // 2 x 64K floats

    convert_bf16<<<dim3(8192), 256, 0, stream>>>(x, wq, wk, wv, wo, xb, wqkvb, wob);
    gemm_qkv<<<dim3(M_/128, 24), 256, 0, stream>>>(xb, wqkvb, qbh, kbh, vt,
                                                   q_scale, k_scale, rope_cos, rope_sin);
    flash_mfma<<<dim3((S_/256)*B_*H_*SPLIT_), 256, 0, stream>>>(qbh, kbh, vt, po, pl);
    gemm_out<<<dim3(M_/64, D_/128), 256, 0, stream>>>(po, pl, wob, out);
}

// Round 14
// 194.102 us; speedup vs baseline: 1.0497x; 1.0497x over previous
//
#include <hip/hip_runtime.h>
#include <hip/hip_bf16.h>

// RoPEAttention B=2 S=2048 D=1024 H=16 HD=64, fp32 in/out.
// R23: byte-exact restore of the R12 build (195.3us measured best).
//      R22's flash dbuf regressed AGAIN (55.2->66.8, VGPR 120->156, occ
//      15.4->10.1) even with R20 ordering: flash's baseline pressure
//      (Oacc 64 + qfrag 32) leaves no headroom for 32 staged-reg lives.
//      Reg-staged dbuf is validated for the GEMMs, falsified 2x for flash.
// R21: gemm_out reg-staged dbuf. R20: gemm_qkv reg-staged dbuf.
// R16: flash Q-block 256, single-buffer 2-barrier staging (measured best).
// ws (shorts): qbh[0,4M) kbh[4M,8M) vt[8M,12M) xb[16M,20M)
//              wqkvb[20M,23M) wob[23M,24M) po[24M,32M) pl(fp32) after.

#define B_ 2
#define S_ 2048
#define D_ 1024
#define H_ 16
#define HD_ 64
#define M_ (B_*S_)
#define SPLIT_ 2
#define KSPAN_ (S_/SPLIT_)    // 1024 keys per split

typedef __attribute__((ext_vector_type(8))) short short8;
typedef __attribute__((ext_vector_type(4))) short short4v;
typedef __attribute__((ext_vector_type(4))) float f32x4;
typedef __attribute__((ext_vector_type(4))) _Float16 half4;
typedef __attribute__((ext_vector_type(8))) _Float16 half8;

static __device__ __forceinline__ short f2bf(float f) {
    __hip_bfloat16 h = __float2bfloat16(f);
    return *reinterpret_cast<short*>(&h);
}
static __device__ __forceinline__ short f2h(float f) {
    _Float16 h = (_Float16)f;
    return *reinterpret_cast<short*>(&h);
}

typedef __attribute__((address_space(1))) const unsigned int gu32_t;
typedef __attribute__((address_space(3))) unsigned int lu32_t;
static __device__ __forceinline__ void gld16(const short* g, short* l) {
    __builtin_amdgcn_global_load_lds((gu32_t*)g, (lu32_t*)l, 16, 0, 0);
}

// ---------------- fp32 -> bf16 convert: x, wq|wk|wv (concat), wo ----------------
__global__ __launch_bounds__(256)
void convert_bf16(const float* __restrict__ x,
                  const float* __restrict__ wq, const float* __restrict__ wk,
                  const float* __restrict__ wv, const float* __restrict__ wo,
                  short* __restrict__ xb, short* __restrict__ wqkvb, short* __restrict__ wob)
{
    const size_t t4 = ((size_t)blockIdx.x * 256 + threadIdx.x) * 4;
    const float* src; short* dst; size_t off, doff;
    if (t4 < 4194304)      { src = x;  dst = xb;    off = t4;           doff = t4; }
    else if (t4 < 5242880) { src = wq; dst = wqkvb; off = t4 - 4194304; doff = t4 - 4194304; }
    else if (t4 < 6291456) { src = wk; dst = wqkvb; off = t4 - 5242880; doff = t4 - 4194304; }
    else if (t4 < 7340032) { src = wv; dst = wqkvb; off = t4 - 6291456; doff = t4 - 4194304; }
    else                   { src = wo; dst = wob;   off = t4 - 7340032; doff = t4 - 7340032; }
    float4 v = *(const float4*)(src + off);
    short4v s = { f2bf(v.x), f2bf(v.y), f2bf(v.z), f2bf(v.w) };
    *(short4v*)(dst + doff) = s;
}

// ---------------- bf16 MFMA GEMM NT 128x128, BK=64 XOR-swizzled, reg-staged dbuf ----------------
// Epilogue: which==0/1 -> fused RMSNorm+RoPE -> Qb/Kb bf16 [B,H,S,HD]
//           which==2   -> Vt f16 [B,H,HD,S]
__global__ __launch_bounds__(256)
void gemm_qkv(const short* __restrict__ A, const short* __restrict__ Bw,
              short* __restrict__ Qb, short* __restrict__ Kb, short* __restrict__ Vt,
              const float* __restrict__ q_scale, const float* __restrict__ k_scale,
              const float* __restrict__ rope_cos, const float* __restrict__ rope_sin)
{
    __shared__ __align__(16) short As[2][128*64];   // 2 x 16KB
    __shared__ __align__(16) short Bs[2][128*64];   // 2 x 16KB  (total 64KB)
    const int tid = threadIdx.x;
    const int w = tid >> 6, lane = tid & 63, quad = lane >> 4, l16 = lane & 15;
    const int wr = w >> 1, wc = w & 1;
    const int bm0 = blockIdx.x * 128, bn0 = blockIdx.y * 128;

    const int row_ = tid >> 3;
    const int kslot = tid & 7;
    const short* gA[4]; const short* gB[4];
    int wo_[4];
    #pragma unroll
    for (int j = 0; j < 4; ++j) {
        const int row = j*32 + row_;
        const int kch = kslot ^ (row & 7);
        gA[j] = A  + (size_t)(bm0 + row) * 1024 + kch*8;
        gB[j] = Bw + (size_t)(bn0 + row) * 1024 + kch*8;
        wo_[j] = row*64 + kslot*8;       // == j*2048 + w*512 + lane*8
    }

    f32x4 acc[4][4];
    #pragma unroll
    for (int i = 0; i < 4; ++i)
        #pragma unroll
        for (int j = 0; j < 4; ++j) acc[i][j] = (f32x4){0.f,0.f,0.f,0.f};

    // prologue: tile0 -> regs -> buf0; tile1 -> regs; barrier
    short8 rA[4], rB[4];
    #pragma unroll
    for (int j = 0; j < 4; ++j) { rA[j] = *(const short8*)gA[j]; rB[j] = *(const short8*)gB[j]; }
    #pragma unroll
    for (int j = 0; j < 4; ++j) {
        *(short8*)(&As[0][wo_[j]]) = rA[j];
        *(short8*)(&Bs[0][wo_[j]]) = rB[j];
    }
    #pragma unroll
    for (int j = 0; j < 4; ++j) { rA[j] = *(const short8*)(gA[j] + 64); rB[j] = *(const short8*)(gB[j] + 64); }
    asm volatile("s_waitcnt lgkmcnt(0)" ::: "memory");
    __builtin_amdgcn_s_barrier();
    __builtin_amdgcn_sched_barrier(0);

    int cur = 0;
    for (int t = 0; t < 16; ++t) {
        // compute tile t from buf[cur]
        short8 af[2][4], bfr[2][4];
        #pragma unroll
        for (int ph = 0; ph < 2; ++ph)
            #pragma unroll
            for (int i = 0; i < 4; ++i) {
                const int ra = wr*64 + i*16 + l16;
                af[ph][i]  = *(const short8*)(&As[cur][ra*64 + (((ph*4 + quad) ^ (ra & 7)) << 3)]);
                const int rb = wc*64 + i*16 + l16;
                bfr[ph][i] = *(const short8*)(&Bs[cur][rb*64 + (((ph*4 + quad) ^ (rb & 7)) << 3)]);
            }
        #pragma unroll
        for (int ph = 0; ph < 2; ++ph)
            #pragma unroll
            for (int i = 0; i < 4; ++i)
                #pragma unroll
                for (int j = 0; j < 4; ++j)
                    acc[i][j] = __builtin_amdgcn_mfma_f32_16x16x32_bf16(af[ph][i], bfr[ph][j], acc[i][j], 0, 0, 0);

        if (t < 15) {
            // commit tile t+1 (in regs since last iter) to the other buffer
            #pragma unroll
            for (int j = 0; j < 4; ++j) {
                *(short8*)(&As[cur ^ 1][wo_[j]]) = rA[j];
                *(short8*)(&Bs[cur ^ 1][wo_[j]]) = rB[j];
            }
            // issue tile t+2 loads (stay in flight across the barrier: no vmcnt drain)
            if (t < 14) {
                const int k0 = (t + 2) * 64;
                #pragma unroll
                for (int j = 0; j < 4; ++j) {
                    rA[j] = *(const short8*)(gA[j] + k0);
                    rB[j] = *(const short8*)(gB[j] + k0);
                }
            }
            asm volatile("s_waitcnt lgkmcnt(0)" ::: "memory");
            __builtin_amdgcn_s_barrier();
            __builtin_amdgcn_sched_barrier(0);
            cur ^= 1;
        }
    }

    const int nbase = bn0 + wc*64;
    const int which = nbase >> 10;
    const int h     = (nbase & 1023) >> 6;

    if (which < 2) {
        const float* sc = which ? k_scale : q_scale;
        short* dst      = which ? Kb : Qb;
        const float fold = which ? 1.0f : 0.18033688011112042f;  // q: (1/8)*log2(e)
        float scv[4];
        #pragma unroll
        for (int j = 0; j < 4; ++j) scv[j] = sc[j*16 + l16];
        #pragma unroll
        for (int i = 0; i < 4; ++i) {
            #pragma unroll
            for (int r = 0; r < 4; ++r) {
                const int m = bm0 + wr*64 + i*16 + quad*4 + r;
                const int b = m >> 11, s = m & (S_-1);
                float ss = 0.f;
                #pragma unroll
                for (int j = 0; j < 4; ++j) ss += acc[i][j][r] * acc[i][j][r];
                #pragma unroll
                for (int msk = 1; msk <= 8; msk <<= 1) ss += __shfl_xor(ss, msk, 64);
                const float rn = rsqrtf(ss * (1.0f/64.0f) + 1e-6f);
                #pragma unroll
                for (int j = 0; j < 4; ++j) {
                    const int hd = j*16 + l16;
                    const float nv = acc[i][j][r] * rn * scv[j];
                    const float c  = rope_cos[s*32 + (hd >> 1)];
                    const float sn = rope_sin[s*32 + (hd >> 1)];
                    const float partner = __shfl_xor(nv, 1, 64);
                    const float o = (hd & 1) ? (partner * sn + nv * c) : (nv * c - partner * sn);
                    dst[(((size_t)b*H_ + h)*S_ + s)*HD_ + hd] = f2bf(o * fold);
                }
            }
        }
    } else {
        #pragma unroll
        for (int i = 0; i < 4; ++i)
            #pragma unroll
            for (int r = 0; r < 4; ++r) {
                const int m = bm0 + wr*64 + i*16 + quad*4 + r;
                const int b = m >> 11, s = m & (S_-1);
                #pragma unroll
                for (int j = 0; j < 4; ++j) {
                    const int hd = j*16 + l16;
                    Vt[(((size_t)b*H_ + h)*HD_ + hd)*S_ + s] = f2h(acc[i][j][r]);
                }
            }
    }
}

// ---------------- out-proj GEMM 64x128, BK=64 XOR-swizzled, reg-staged dbuf ----------------
__global__ __launch_bounds__(256)
void gemm_out(const short* __restrict__ po, const float* __restrict__ pl,
              const short* __restrict__ Bw, float* __restrict__ C)
{
    __shared__ __align__(16) short As[2][64*64];    // 2 x 8KB
    __shared__ __align__(16) short Bs[2][128*64];   // 2 x 16KB (total 48KB)
    const int tid = threadIdx.x;
    const int w = tid >> 6, lane = tid & 63, quad = lane >> 4, l16 = lane & 15;
    const int bm0 = blockIdx.x * 64, bn0 = blockIdx.y * 128;

    // B reg-staging (same slot math as gemm_qkv)
    const int row_ = tid >> 3;
    const int kslot = tid & 7;
    const short* gB[4];
    int woB[4];
    #pragma unroll
    for (int j = 0; j < 4; ++j) {
        const int row = j*32 + row_;
        const int kch = kslot ^ (row & 7);
        gB[j] = Bw + (size_t)(bn0 + row) * 1024 + kch*8;
        woB[j] = row*64 + kslot*8;
    }

    // A production: thread -> row srow, chunks ch0, ch0+1 (8 shorts each)
    const int srow = tid >> 2;          // 0..63
    const int ch0  = (tid & 3) * 2;     // 0,2,4,6
    const int m = bm0 + srow;
    const int b = m >> 11, s = m & (S_-1);
    const short* p0 = po +            (size_t)m * 1024;
    const short* p1 = po + 4194304 + (size_t)m * 1024;

    float inv[16];
    #pragma unroll
    for (int h = 0; h < 16; ++h)
        inv[h] = 1.0f / (pl[((size_t)(b*16 + h))*S_ + s] + pl[65536 + ((size_t)(b*16 + h))*S_ + s]);

    f32x4 acc[4][2];
    #pragma unroll
    for (int i = 0; i < 4; ++i) {
        acc[i][0] = (f32x4){0.f,0.f,0.f,0.f};
        acc[i][1] = (f32x4){0.f,0.f,0.f,0.f};
    }

    // ---- prologue: tile0 -> regs -> buf0; tile1 -> regs; barrier ----
    short8 rB[4];
    half8 d00, d01, d10, d11;
    #pragma unroll
    for (int j = 0; j < 4; ++j) rB[j] = *(const short8*)gB[j];
    d00 = *(const half8*)(p0 + ch0*8);
    d01 = *(const half8*)(p1 + ch0*8);
    d10 = *(const half8*)(p0 + ch0*8 + 8);
    d11 = *(const half8*)(p1 + ch0*8 + 8);
    {
        const float invh = inv[0];
        short8 a0, a1;
        #pragma unroll
        for (int j = 0; j < 8; ++j) {
            a0[j] = f2bf(((float)d00[j] + (float)d01[j]) * invh);
            a1[j] = f2bf(((float)d10[j] + (float)d11[j]) * invh);
        }
        *(short8*)(&As[0][srow*64 + (((ch0    ) ^ (srow & 7)) << 3)]) = a0;
        *(short8*)(&As[0][srow*64 + (((ch0 + 1) ^ (srow & 7)) << 3)]) = a1;
        #pragma unroll
        for (int j = 0; j < 4; ++j)
            *(short8*)(&Bs[0][woB[j]]) = rB[j];
    }
    #pragma unroll
    for (int j = 0; j < 4; ++j) rB[j] = *(const short8*)(gB[j] + 64);
    d00 = *(const half8*)(p0 + 64 + ch0*8);
    d01 = *(const half8*)(p1 + 64 + ch0*8);
    d10 = *(const half8*)(p0 + 64 + ch0*8 + 8);
    d11 = *(const half8*)(p1 + 64 + ch0*8 + 8);
    asm volatile("s_waitcnt lgkmcnt(0)" ::: "memory");
    __builtin_amdgcn_s_barrier();
    __builtin_amdgcn_sched_barrier(0);

    int cur = 0;
    for (int t = 0; t < 16; ++t) {
        // compute tile t from buf[cur]
        #pragma unroll
        for (int ph = 0; ph < 2; ++ph) {
            short8 af[4], bfr[2];
            #pragma unroll
            for (int i = 0; i < 4; ++i) {
                const int ra = i*16 + l16;
                af[i] = *(const short8*)(&As[cur][ra*64 + (((ph*4 + quad) ^ (ra & 7)) << 3)]);
            }
            #pragma unroll
            for (int j = 0; j < 2; ++j) {
                const int rb = w*32 + j*16 + l16;
                bfr[j] = *(const short8*)(&Bs[cur][rb*64 + (((ph*4 + quad) ^ (rb & 7)) << 3)]);
            }
            #pragma unroll
            for (int i = 0; i < 4; ++i)
                #pragma unroll
                for (int j = 0; j < 2; ++j)
                    acc[i][j] = __builtin_amdgcn_mfma_f32_16x16x32_bf16(af[i], bfr[j], acc[i][j], 0, 0, 0);
        }

        if (t < 15) {
            // commit tile t+1 (regs) to the other buffer
            const float invh = inv[t + 1];
            short8 a0, a1;
            #pragma unroll
            for (int j = 0; j < 8; ++j) {
                a0[j] = f2bf(((float)d00[j] + (float)d01[j]) * invh);
                a1[j] = f2bf(((float)d10[j] + (float)d11[j]) * invh);
            }
            *(short8*)(&As[cur ^ 1][srow*64 + (((ch0    ) ^ (srow & 7)) << 3)]) = a0;
            *(short8*)(&As[cur ^ 1][srow*64 + (((ch0 + 1) ^ (srow & 7)) << 3)]) = a1;
            #pragma unroll
            for (int j = 0; j < 4; ++j)
                *(short8*)(&Bs[cur ^ 1][woB[j]]) = rB[j];
            // issue tile t+2 loads (no vmcnt drain; stay in flight across barrier)
            if (t < 14) {
                const int k0 = (t + 2) * 64;
                #pragma unroll
                for (int j = 0; j < 4; ++j) rB[j] = *(const short8*)(gB[j] + k0);
                d00 = *(const half8*)(p0 + k0 + ch0*8);
                d01 = *(const half8*)(p1 + k0 + ch0*8);
                d10 = *(const half8*)(p0 + k0 + ch0*8 + 8);
                d11 = *(const half8*)(p1 + k0 + ch0*8 + 8);
            }
            asm volatile("s_waitcnt lgkmcnt(0)" ::: "memory");
            __builtin_amdgcn_s_barrier();
            __builtin_amdgcn_sched_barrier(0);
            cur ^= 1;
        }
    }

    #pragma unroll
    for (int i = 0; i < 4; ++i)
        #pragma unroll
        for (int r = 0; r < 4; ++r) {
            const int mm = bm0 + i*16 + quad*4 + r;
            #pragma unroll
            for (int j = 0; j < 2; ++j) {
                const int n = bn0 + w*32 + j*16 + l16;
                C[(size_t)mm*1024 + n] = acc[i][j][r];
            }
        }
}

// ---------------- MFMA flash attention partial, split-K=2, XCD-swizzled, Q-block 256 ----------------
__global__ __launch_bounds__(256)
void flash_mfma(const short* __restrict__ qb, const short* __restrict__ kb,
                const short* __restrict__ vt, short* __restrict__ po, float* __restrict__ pl)
{
    __shared__ __align__(16) short Ks[64*64];
    __shared__ __align__(16) short Vs[64*64];   // f16 bits, [d][key] swizzled

    const int id   = blockIdx.x;
    const int xcd  = id & 7;
    const int rest = id >> 3;
    const int qblk = rest & 7;                // 8 q-blocks of 256
    const int g    = (rest >> 3) * 8 + xcd;   // (bh,sp) group 0..63
    const int bh   = g >> 1;
    const int sp   = g & 1;

    const int tid  = threadIdx.x;
    const int wv   = tid >> 6;
    const int lane = tid & 63;
    const int quad = lane >> 4;
    const int l16  = lane & 15;
    const int b    = bh >> 4, h = bh & (H_-1);
    const int q0   = qblk * 256 + wv * 64;    // 64 q-rows per wave
    const int kt0  = sp * KSPAN_;
    const size_t hbase = (size_t)bh * S_ * HD_;
    const size_t vbase = (size_t)bh * HD_ * S_;
    short* po_sp = po + (size_t)sp * 4194304;
    float* pl_sp = pl + (size_t)sp * 65536;

    const int c0r = tid >> 3,       c0c = tid & 7;
    const int c1r = (tid+256) >> 3, c1c = (tid+256) & 7;

    short8 qfrag[4][2];
    #pragma unroll
    for (int qf = 0; qf < 4; ++qf)
        #pragma unroll
        for (int c = 0; c < 2; ++c)
            qfrag[qf][c] = *(const short8*)(qb + hbase + (size_t)(q0 + qf*16 + l16)*HD_ + c*32 + quad*8);

    f32x4 Oacc[4][4];
    #pragma unroll
    for (int qf = 0; qf < 4; ++qf)
        #pragma unroll
        for (int dt = 0; dt < 4; ++dt) Oacc[qf][dt] = (f32x4){0.f,0.f,0.f,0.f};
    float l_lane[4] = {0.f, 0.f, 0.f, 0.f};

    short8 rk0 = *(const short8*)(kb + hbase + (size_t)(kt0 + c0r)*HD_ + c0c*8);
    short8 rk1 = *(const short8*)(kb + hbase + (size_t)(kt0 + c1r)*HD_ + c1c*8);
    short8 rv0 = *(const short8*)(vt + vbase + (size_t)c0r*S_ + kt0 + c0c*8);
    short8 rv1 = *(const short8*)(vt + vbase + (size_t)c1r*S_ + kt0 + c1c*8);

    #pragma unroll 1
    for (int t = 0; t < KSPAN_/64; ++t) {
        __syncthreads();
        *(short8*)(Ks + c0r*64 + ((c0c ^ (c0r & 7)) << 3)) = rk0;
        *(short8*)(Ks + c1r*64 + ((c1c ^ (c1r & 7)) << 3)) = rk1;
        *(short8*)(Vs + c0r*64 + ((c0c ^ (c0r & 7)) << 3)) = rv0;
        *(short8*)(Vs + c1r*64 + ((c1c ^ (c1r & 7)) << 3)) = rv1;
        __syncthreads();
        if (t < KSPAN_/64 - 1) {
            const int ktn = kt0 + (t+1)*64;
            rk0 = *(const short8*)(kb + hbase + (size_t)(ktn + c0r)*HD_ + c0c*8);
            rk1 = *(const short8*)(kb + hbase + (size_t)(ktn + c1r)*HD_ + c1c*8);
            rv0 = *(const short8*)(vt + vbase + (size_t)c0r*S_ + ktn + c0c*8);
            rv1 = *(const short8*)(vt + vbase + (size_t)c1r*S_ + ktn + c1c*8);
        }

        #pragma unroll
        for (int st = 0; st < 4; ++st) {
            short8 kf0 = *(const short8*)(Ks + (st*16 + l16)*64 + (((quad    ) ^ (l16 & 7)) << 3));
            short8 kf1 = *(const short8*)(Ks + (st*16 + l16)*64 + (((4 + quad) ^ (l16 & 7)) << 3));
            const int ch16 = st*2 + (quad >> 1);
            const int sw   = ((ch16 ^ (l16 & 7)) << 3) + (quad & 1)*4;
            half4 va[4];
            #pragma unroll
            for (int dt = 0; dt < 4; ++dt)
                va[dt] = *(const half4*)(Vs + (dt*16 + l16)*64 + sw);
            #pragma unroll
            for (int qf = 0; qf < 4; ++qf) {
                f32x4 acc = (f32x4){0.f,0.f,0.f,0.f};
                acc = __builtin_amdgcn_mfma_f32_16x16x32_bf16(kf0, qfrag[qf][0], acc, 0, 0, 0);
                acc = __builtin_amdgcn_mfma_f32_16x16x32_bf16(kf1, qfrag[qf][1], acc, 0, 0, 0);
                half4 pb;
                #pragma unroll
                for (int r = 0; r < 4; ++r) {
                    float p = __builtin_amdgcn_exp2f(acc[r] - 12.0f);
                    l_lane[qf] += p;
                    pb[r] = (_Float16)p;
                }
                #pragma unroll
                for (int dt = 0; dt < 4; ++dt)
                    Oacc[qf][dt] = __builtin_amdgcn_mfma_f32_16x16x16f16(va[dt], pb, Oacc[qf][dt], 0, 0, 0);
            }
        }
    }

    #pragma unroll
    for (int qf = 0; qf < 4; ++qf) {
        l_lane[qf] += __shfl_xor(l_lane[qf], 16, 64);
        l_lane[qf] += __shfl_xor(l_lane[qf], 32, 64);
        if (quad == 0) pl_sp[(size_t)bh*S_ + q0 + qf*16 + l16] = l_lane[qf];
    }
    #pragma unroll
    for (int qf = 0; qf < 4; ++qf) {
        const int s = q0 + qf*16 + l16;
        #pragma unroll
        for (int dt = 0; dt < 4; ++dt) {
            short4v o;
            #pragma unroll
            for (int r = 0; r < 4; ++r) o[r] = f2h(Oacc[qf][dt][r]);
            *(short4v*)(po_sp + (((size_t)b*S_ + s)*H_ + h)*HD_ + dt*16 + quad*4) = o;
        }
    }
}

extern "C" void kernel_launch(void* const* d_in, const int* in_sizes, int n_in,
                              void* d_out, int out_size, void* d_ws, size_t ws_size,
                              hipStream_t stream)
{
    (void)in_sizes; (void)n_in; (void)out_size; (void)ws_size;
    const float* x        = (const float*)d_in[0];
    const float* wq       = (const float*)d_in[1];
    const float* wk       = (const float*)d_in[2];
    const float* wv       = (const float*)d_in[3];
    const float* wo       = (const float*)d_in[4];
    const float* q_scale  = (const float*)d_in[5];
    const float* k_scale  = (const float*)d_in[6];
    const float* rope_cos = (const float*)d_in[7];
    const float* rope_sin = (const float*)d_in[8];
    float* out = (float*)d_out;
    short* ws  = (short*)d_ws;

    short* qbh   = ws;                 // 4M shorts
    short* kbh   = ws + 4194304;
    short* vt    = ws + 8388608;
    short* xb    = ws + 16777216;
    short* wqkvb = ws + 20971520;      // 3M shorts
    short* wob   = ws + 24117248;      // 1M shorts
    short* po    = ws + 25165824;      // 2 x 4M shorts (f16)
    float* pl    = (float*)(ws + 33554432);  // 2 x 64K floats

    convert_bf16<<<dim3(8192), 256, 0, stream>>>(x, wq, wk, wv, wo, xb, wqkvb, wob);
    gemm_qkv<<<dim3(M_/128, 24), 256, 0, stream>>>(xb, wqkvb, qbh, kbh, vt,
                                                   q_scale, k_scale, rope_cos, rope_sin);
    flash_mfma<<<dim3((S_/256)*B_*H_*SPLIT_), 256, 0, stream>>>(qbh, kbh, vt, po, pl);
    gemm_out<<<dim3(M_/64, D_/128), 256, 0, stream>>>(po, pl, wob, out);
}

// Round 15
// 193.795 us; speedup vs baseline: 1.0514x; 1.0016x over previous
//
#include <hip/hip_runtime.h>
#include <hip/hip_bf16.h>

// RoPEAttention B=2 S=2048 D=1024 H=16 HD=64, fp32 in/out.
// R24 (final): byte-exact lock-in of the measured-best build (194.1us, R14).
//      Session: 210.0 -> 194.1 (-7.6%). Wins: gemm_qkv reg-staged dbuf (R20,
//      71->~50us: hipcc serializes gld16 dbuf on LDS-DMA alias ambiguity;
//      precise reg deps fix it), gemm_out reg-staged dbuf (R21), flash Q-block
//      256 (R16). Falsified on flash: setprio(-6%), PV K=32(-5%), direct-L2
//      (-228%), LDS dbuf 2x (VGPR pressure), SPLIT_4 (coupling). Flash is
//      latency-bound (MFMA 37/VALU 43/HBM 8, 2 blocks/CU); next lever would be
//      4 blocks/CU via SPLIT_4, untestable safely under whole-file coupling.
// ws (shorts): qbh[0,4M) kbh[4M,8M) vt[8M,12M) xb[16M,20M)
//              wqkvb[20M,23M) wob[23M,24M) po[24M,32M) pl(fp32) after.

#define B_ 2
#define S_ 2048
#define D_ 1024
#define H_ 16
#define HD_ 64
#define M_ (B_*S_)
#define SPLIT_ 2
#define KSPAN_ (S_/SPLIT_)    // 1024 keys per split

typedef __attribute__((ext_vector_type(8))) short short8;
typedef __attribute__((ext_vector_type(4))) short short4v;
typedef __attribute__((ext_vector_type(4))) float f32x4;
typedef __attribute__((ext_vector_type(4))) _Float16 half4;
typedef __attribute__((ext_vector_type(8))) _Float16 half8;

static __device__ __forceinline__ short f2bf(float f) {
    __hip_bfloat16 h = __float2bfloat16(f);
    return *reinterpret_cast<short*>(&h);
}
static __device__ __forceinline__ short f2h(float f) {
    _Float16 h = (_Float16)f;
    return *reinterpret_cast<short*>(&h);
}

typedef __attribute__((address_space(1))) const unsigned int gu32_t;
typedef __attribute__((address_space(3))) unsigned int lu32_t;
static __device__ __forceinline__ void gld16(const short* g, short* l) {
    __builtin_amdgcn_global_load_lds((gu32_t*)g, (lu32_t*)l, 16, 0, 0);
}

// ---------------- fp32 -> bf16 convert: x, wq|wk|wv (concat), wo ----------------
__global__ __launch_bounds__(256)
void convert_bf16(const float* __restrict__ x,
                  const float* __restrict__ wq, const float* __restrict__ wk,
                  const float* __restrict__ wv, const float* __restrict__ wo,
                  short* __restrict__ xb, short* __restrict__ wqkvb, short* __restrict__ wob)
{
    const size_t t4 = ((size_t)blockIdx.x * 256 + threadIdx.x) * 4;
    const float* src; short* dst; size_t off, doff;
    if (t4 < 4194304)      { src = x;  dst = xb;    off = t4;           doff = t4; }
    else if (t4 < 5242880) { src = wq; dst = wqkvb; off = t4 - 4194304; doff = t4 - 4194304; }
    else if (t4 < 6291456) { src = wk; dst = wqkvb; off = t4 - 5242880; doff = t4 - 4194304; }
    else if (t4 < 7340032) { src = wv; dst = wqkvb; off = t4 - 6291456; doff = t4 - 4194304; }
    else                   { src = wo; dst = wob;   off = t4 - 7340032; doff = t4 - 7340032; }
    float4 v = *(const float4*)(src + off);
    short4v s = { f2bf(v.x), f2bf(v.y), f2bf(v.z), f2bf(v.w) };
    *(short4v*)(dst + doff) = s;
}

// ---------------- bf16 MFMA GEMM NT 128x128, BK=64 XOR-swizzled, reg-staged dbuf ----------------
// Epilogue: which==0/1 -> fused RMSNorm+RoPE -> Qb/Kb bf16 [B,H,S,HD]
//           which==2   -> Vt f16 [B,H,HD,S]
__global__ __launch_bounds__(256)
void gemm_qkv(const short* __restrict__ A, const short* __restrict__ Bw,
              short* __restrict__ Qb, short* __restrict__ Kb, short* __restrict__ Vt,
              const float* __restrict__ q_scale, const float* __restrict__ k_scale,
              const float* __restrict__ rope_cos, const float* __restrict__ rope_sin)
{
    __shared__ __align__(16) short As[2][128*64];   // 2 x 16KB
    __shared__ __align__(16) short Bs[2][128*64];   // 2 x 16KB  (total 64KB)
    const int tid = threadIdx.x;
    const int w = tid >> 6, lane = tid & 63, quad = lane >> 4, l16 = lane & 15;
    const int wr = w >> 1, wc = w & 1;
    const int bm0 = blockIdx.x * 128, bn0 = blockIdx.y * 128;

    const int row_ = tid >> 3;
    const int kslot = tid & 7;
    const short* gA[4]; const short* gB[4];
    int wo_[4];
    #pragma unroll
    for (int j = 0; j < 4; ++j) {
        const int row = j*32 + row_;
        const int kch = kslot ^ (row & 7);
        gA[j] = A  + (size_t)(bm0 + row) * 1024 + kch*8;
        gB[j] = Bw + (size_t)(bn0 + row) * 1024 + kch*8;
        wo_[j] = row*64 + kslot*8;       // == j*2048 + w*512 + lane*8
    }

    f32x4 acc[4][4];
    #pragma unroll
    for (int i = 0; i < 4; ++i)
        #pragma unroll
        for (int j = 0; j < 4; ++j) acc[i][j] = (f32x4){0.f,0.f,0.f,0.f};

    // prologue: tile0 -> regs -> buf0; tile1 -> regs; barrier
    short8 rA[4], rB[4];
    #pragma unroll
    for (int j = 0; j < 4; ++j) { rA[j] = *(const short8*)gA[j]; rB[j] = *(const short8*)gB[j]; }
    #pragma unroll
    for (int j = 0; j < 4; ++j) {
        *(short8*)(&As[0][wo_[j]]) = rA[j];
        *(short8*)(&Bs[0][wo_[j]]) = rB[j];
    }
    #pragma unroll
    for (int j = 0; j < 4; ++j) { rA[j] = *(const short8*)(gA[j] + 64); rB[j] = *(const short8*)(gB[j] + 64); }
    asm volatile("s_waitcnt lgkmcnt(0)" ::: "memory");
    __builtin_amdgcn_s_barrier();
    __builtin_amdgcn_sched_barrier(0);

    int cur = 0;
    for (int t = 0; t < 16; ++t) {
        // compute tile t from buf[cur]
        short8 af[2][4], bfr[2][4];
        #pragma unroll
        for (int ph = 0; ph < 2; ++ph)
            #pragma unroll
            for (int i = 0; i < 4; ++i) {
                const int ra = wr*64 + i*16 + l16;
                af[ph][i]  = *(const short8*)(&As[cur][ra*64 + (((ph*4 + quad) ^ (ra & 7)) << 3)]);
                const int rb = wc*64 + i*16 + l16;
                bfr[ph][i] = *(const short8*)(&Bs[cur][rb*64 + (((ph*4 + quad) ^ (rb & 7)) << 3)]);
            }
        #pragma unroll
        for (int ph = 0; ph < 2; ++ph)
            #pragma unroll
            for (int i = 0; i < 4; ++i)
                #pragma unroll
                for (int j = 0; j < 4; ++j)
                    acc[i][j] = __builtin_amdgcn_mfma_f32_16x16x32_bf16(af[ph][i], bfr[ph][j], acc[i][j], 0, 0, 0);

        if (t < 15) {
            // commit tile t+1 (in regs since last iter) to the other buffer
            #pragma unroll
            for (int j = 0; j < 4; ++j) {
                *(short8*)(&As[cur ^ 1][wo_[j]]) = rA[j];
                *(short8*)(&Bs[cur ^ 1][wo_[j]]) = rB[j];
            }
            // issue tile t+2 loads (stay in flight across the barrier: no vmcnt drain)
            if (t < 14) {
                const int k0 = (t + 2) * 64;
                #pragma unroll
                for (int j = 0; j < 4; ++j) {
                    rA[j] = *(const short8*)(gA[j] + k0);
                    rB[j] = *(const short8*)(gB[j] + k0);
                }
            }
            asm volatile("s_waitcnt lgkmcnt(0)" ::: "memory");
            __builtin_amdgcn_s_barrier();
            __builtin_amdgcn_sched_barrier(0);
            cur ^= 1;
        }
    }

    const int nbase = bn0 + wc*64;
    const int which = nbase >> 10;
    const int h     = (nbase & 1023) >> 6;

    if (which < 2) {
        const float* sc = which ? k_scale : q_scale;
        short* dst      = which ? Kb : Qb;
        const float fold = which ? 1.0f : 0.18033688011112042f;  // q: (1/8)*log2(e)
        float scv[4];
        #pragma unroll
        for (int j = 0; j < 4; ++j) scv[j] = sc[j*16 + l16];
        #pragma unroll
        for (int i = 0; i < 4; ++i) {
            #pragma unroll
            for (int r = 0; r < 4; ++r) {
                const int m = bm0 + wr*64 + i*16 + quad*4 + r;
                const int b = m >> 11, s = m & (S_-1);
                float ss = 0.f;
                #pragma unroll
                for (int j = 0; j < 4; ++j) ss += acc[i][j][r] * acc[i][j][r];
                #pragma unroll
                for (int msk = 1; msk <= 8; msk <<= 1) ss += __shfl_xor(ss, msk, 64);
                const float rn = rsqrtf(ss * (1.0f/64.0f) + 1e-6f);
                #pragma unroll
                for (int j = 0; j < 4; ++j) {
                    const int hd = j*16 + l16;
                    const float nv = acc[i][j][r] * rn * scv[j];
                    const float c  = rope_cos[s*32 + (hd >> 1)];
                    const float sn = rope_sin[s*32 + (hd >> 1)];
                    const float partner = __shfl_xor(nv, 1, 64);
                    const float o = (hd & 1) ? (partner * sn + nv * c) : (nv * c - partner * sn);
                    dst[(((size_t)b*H_ + h)*S_ + s)*HD_ + hd] = f2bf(o * fold);
                }
            }
        }
    } else {
        #pragma unroll
        for (int i = 0; i < 4; ++i)
            #pragma unroll
            for (int r = 0; r < 4; ++r) {
                const int m = bm0 + wr*64 + i*16 + quad*4 + r;
                const int b = m >> 11, s = m & (S_-1);
                #pragma unroll
                for (int j = 0; j < 4; ++j) {
                    const int hd = j*16 + l16;
                    Vt[(((size_t)b*H_ + h)*HD_ + hd)*S_ + s] = f2h(acc[i][j][r]);
                }
            }
    }
}

// ---------------- out-proj GEMM 64x128, BK=64 XOR-swizzled, reg-staged dbuf ----------------
__global__ __launch_bounds__(256)
void gemm_out(const short* __restrict__ po, const float* __restrict__ pl,
              const short* __restrict__ Bw, float* __restrict__ C)
{
    __shared__ __align__(16) short As[2][64*64];    // 2 x 8KB
    __shared__ __align__(16) short Bs[2][128*64];   // 2 x 16KB (total 48KB)
    const int tid = threadIdx.x;
    const int w = tid >> 6, lane = tid & 63, quad = lane >> 4, l16 = lane & 15;
    const int bm0 = blockIdx.x * 64, bn0 = blockIdx.y * 128;

    // B reg-staging (same slot math as gemm_qkv)
    const int row_ = tid >> 3;
    const int kslot = tid & 7;
    const short* gB[4];
    int woB[4];
    #pragma unroll
    for (int j = 0; j < 4; ++j) {
        const int row = j*32 + row_;
        const int kch = kslot ^ (row & 7);
        gB[j] = Bw + (size_t)(bn0 + row) * 1024 + kch*8;
        woB[j] = row*64 + kslot*8;
    }

    // A production: thread -> row srow, chunks ch0, ch0+1 (8 shorts each)
    const int srow = tid >> 2;          // 0..63
    const int ch0  = (tid & 3) * 2;     // 0,2,4,6
    const int m = bm0 + srow;
    const int b = m >> 11, s = m & (S_-1);
    const short* p0 = po +            (size_t)m * 1024;
    const short* p1 = po + 4194304 + (size_t)m * 1024;

    float inv[16];
    #pragma unroll
    for (int h = 0; h < 16; ++h)
        inv[h] = 1.0f / (pl[((size_t)(b*16 + h))*S_ + s] + pl[65536 + ((size_t)(b*16 + h))*S_ + s]);

    f32x4 acc[4][2];
    #pragma unroll
    for (int i = 0; i < 4; ++i) {
        acc[i][0] = (f32x4){0.f,0.f,0.f,0.f};
        acc[i][1] = (f32x4){0.f,0.f,0.f,0.f};
    }

    // ---- prologue: tile0 -> regs -> buf0; tile1 -> regs; barrier ----
    short8 rB[4];
    half8 d00, d01, d10, d11;
    #pragma unroll
    for (int j = 0; j < 4; ++j) rB[j] = *(const short8*)gB[j];
    d00 = *(const half8*)(p0 + ch0*8);
    d01 = *(const half8*)(p1 + ch0*8);
    d10 = *(const half8*)(p0 + ch0*8 + 8);
    d11 = *(const half8*)(p1 + ch0*8 + 8);
    {
        const float invh = inv[0];
        short8 a0, a1;
        #pragma unroll
        for (int j = 0; j < 8; ++j) {
            a0[j] = f2bf(((float)d00[j] + (float)d01[j]) * invh);
            a1[j] = f2bf(((float)d10[j] + (float)d11[j]) * invh);
        }
        *(short8*)(&As[0][srow*64 + (((ch0    ) ^ (srow & 7)) << 3)]) = a0;
        *(short8*)(&As[0][srow*64 + (((ch0 + 1) ^ (srow & 7)) << 3)]) = a1;
        #pragma unroll
        for (int j = 0; j < 4; ++j)
            *(short8*)(&Bs[0][woB[j]]) = rB[j];
    }
    #pragma unroll
    for (int j = 0; j < 4; ++j) rB[j] = *(const short8*)(gB[j] + 64);
    d00 = *(const half8*)(p0 + 64 + ch0*8);
    d01 = *(const half8*)(p1 + 64 + ch0*8);
    d10 = *(const half8*)(p0 + 64 + ch0*8 + 8);
    d11 = *(const half8*)(p1 + 64 + ch0*8 + 8);
    asm volatile("s_waitcnt lgkmcnt(0)" ::: "memory");
    __builtin_amdgcn_s_barrier();
    __builtin_amdgcn_sched_barrier(0);

    int cur = 0;
    for (int t = 0; t < 16; ++t) {
        // compute tile t from buf[cur]
        #pragma unroll
        for (int ph = 0; ph < 2; ++ph) {
            short8 af[4], bfr[2];
            #pragma unroll
            for (int i = 0; i < 4; ++i) {
                const int ra = i*16 + l16;
                af[i] = *(const short8*)(&As[cur][ra*64 + (((ph*4 + quad) ^ (ra & 7)) << 3)]);
            }
            #pragma unroll
            for (int j = 0; j < 2; ++j) {
                const int rb = w*32 + j*16 + l16;
                bfr[j] = *(const short8*)(&Bs[cur][rb*64 + (((ph*4 + quad) ^ (rb & 7)) << 3)]);
            }
            #pragma unroll
            for (int i = 0; i < 4; ++i)
                #pragma unroll
                for (int j = 0; j < 2; ++j)
                    acc[i][j] = __builtin_amdgcn_mfma_f32_16x16x32_bf16(af[i], bfr[j], acc[i][j], 0, 0, 0);
        }

        if (t < 15) {
            // commit tile t+1 (regs) to the other buffer
            const float invh = inv[t + 1];
            short8 a0, a1;
            #pragma unroll
            for (int j = 0; j < 8; ++j) {
                a0[j] = f2bf(((float)d00[j] + (float)d01[j]) * invh);
                a1[j] = f2bf(((float)d10[j] + (float)d11[j]) * invh);
            }
            *(short8*)(&As[cur ^ 1][srow*64 + (((ch0    ) ^ (srow & 7)) << 3)]) = a0;
            *(short8*)(&As[cur ^ 1][srow*64 + (((ch0 + 1) ^ (srow & 7)) << 3)]) = a1;
            #pragma unroll
            for (int j = 0; j < 4; ++j)
                *(short8*)(&Bs[cur ^ 1][woB[j]]) = rB[j];
            // issue tile t+2 loads (no vmcnt drain; stay in flight across barrier)
            if (t < 14) {
                const int k0 = (t + 2) * 64;
                #pragma unroll
                for (int j = 0; j < 4; ++j) rB[j] = *(const short8*)(gB[j] + k0);
                d00 = *(const half8*)(p0 + k0 + ch0*8);
                d01 = *(const half8*)(p1 + k0 + ch0*8);
                d10 = *(const half8*)(p0 + k0 + ch0*8 + 8);
                d11 = *(const half8*)(p1 + k0 + ch0*8 + 8);
            }
            asm volatile("s_waitcnt lgkmcnt(0)" ::: "memory");
            __builtin_amdgcn_s_barrier();
            __builtin_amdgcn_sched_barrier(0);
            cur ^= 1;
        }
    }

    #pragma unroll
    for (int i = 0; i < 4; ++i)
        #pragma unroll
        for (int r = 0; r < 4; ++r) {
            const int mm = bm0 + i*16 + quad*4 + r;
            #pragma unroll
            for (int j = 0; j < 2; ++j) {
                const int n = bn0 + w*32 + j*16 + l16;
                C[(size_t)mm*1024 + n] = acc[i][j][r];
            }
        }
}

// ---------------- MFMA flash attention partial, split-K=2, XCD-swizzled, Q-block 256 ----------------
__global__ __launch_bounds__(256)
void flash_mfma(const short* __restrict__ qb, const short* __restrict__ kb,
                const short* __restrict__ vt, short* __restrict__ po, float* __restrict__ pl)
{
    __shared__ __align__(16) short Ks[64*64];
    __shared__ __align__(16) short Vs[64*64];   // f16 bits, [d][key] swizzled

    const int id   = blockIdx.x;
    const int xcd  = id & 7;
    const int rest = id >> 3;
    const int qblk = rest & 7;                // 8 q-blocks of 256
    const int g    = (rest >> 3) * 8 + xcd;   // (bh,sp) group 0..63
    const int bh   = g >> 1;
    const int sp   = g & 1;

    const int tid  = threadIdx.x;
    const int wv   = tid >> 6;
    const int lane = tid & 63;
    const int quad = lane >> 4;
    const int l16  = lane & 15;
    const int b    = bh >> 4, h = bh & (H_-1);
    const int q0   = qblk * 256 + wv * 64;    // 64 q-rows per wave
    const int kt0  = sp * KSPAN_;
    const size_t hbase = (size_t)bh * S_ * HD_;
    const size_t vbase = (size_t)bh * HD_ * S_;
    short* po_sp = po + (size_t)sp * 4194304;
    float* pl_sp = pl + (size_t)sp * 65536;

    const int c0r = tid >> 3,       c0c = tid & 7;
    const int c1r = (tid+256) >> 3, c1c = (tid+256) & 7;

    short8 qfrag[4][2];
    #pragma unroll
    for (int qf = 0; qf < 4; ++qf)
        #pragma unroll
        for (int c = 0; c < 2; ++c)
            qfrag[qf][c] = *(const short8*)(qb + hbase + (size_t)(q0 + qf*16 + l16)*HD_ + c*32 + quad*8);

    f32x4 Oacc[4][4];
    #pragma unroll
    for (int qf = 0; qf < 4; ++qf)
        #pragma unroll
        for (int dt = 0; dt < 4; ++dt) Oacc[qf][dt] = (f32x4){0.f,0.f,0.f,0.f};
    float l_lane[4] = {0.f, 0.f, 0.f, 0.f};

    short8 rk0 = *(const short8*)(kb + hbase + (size_t)(kt0 + c0r)*HD_ + c0c*8);
    short8 rk1 = *(const short8*)(kb + hbase + (size_t)(kt0 + c1r)*HD_ + c1c*8);
    short8 rv0 = *(const short8*)(vt + vbase + (size_t)c0r*S_ + kt0 + c0c*8);
    short8 rv1 = *(const short8*)(vt + vbase + (size_t)c1r*S_ + kt0 + c1c*8);

    #pragma unroll 1
    for (int t = 0; t < KSPAN_/64; ++t) {
        __syncthreads();
        *(short8*)(Ks + c0r*64 + ((c0c ^ (c0r & 7)) << 3)) = rk0;
        *(short8*)(Ks + c1r*64 + ((c1c ^ (c1r & 7)) << 3)) = rk1;
        *(short8*)(Vs + c0r*64 + ((c0c ^ (c0r & 7)) << 3)) = rv0;
        *(short8*)(Vs + c1r*64 + ((c1c ^ (c1r & 7)) << 3)) = rv1;
        __syncthreads();
        if (t < KSPAN_/64 - 1) {
            const int ktn = kt0 + (t+1)*64;
            rk0 = *(const short8*)(kb + hbase + (size_t)(ktn + c0r)*HD_ + c0c*8);
            rk1 = *(const short8*)(kb + hbase + (size_t)(ktn + c1r)*HD_ + c1c*8);
            rv0 = *(const short8*)(vt + vbase + (size_t)c0r*S_ + ktn + c0c*8);
            rv1 = *(const short8*)(vt + vbase + (size_t)c1r*S_ + ktn + c1c*8);
        }

        #pragma unroll
        for (int st = 0; st < 4; ++st) {
            short8 kf0 = *(const short8*)(Ks + (st*16 + l16)*64 + (((quad    ) ^ (l16 & 7)) << 3));
            short8 kf1 = *(const short8*)(Ks + (st*16 + l16)*64 + (((4 + quad) ^ (l16 & 7)) << 3));
            const int ch16 = st*2 + (quad >> 1);
            const int sw   = ((ch16 ^ (l16 & 7)) << 3) + (quad & 1)*4;
            half4 va[4];
            #pragma unroll
            for (int dt = 0; dt < 4; ++dt)
                va[dt] = *(const half4*)(Vs + (dt*16 + l16)*64 + sw);
            #pragma unroll
            for (int qf = 0; qf < 4; ++qf) {
                f32x4 acc = (f32x4){0.f,0.f,0.f,0.f};
                acc = __builtin_amdgcn_mfma_f32_16x16x32_bf16(kf0, qfrag[qf][0], acc, 0, 0, 0);
                acc = __builtin_amdgcn_mfma_f32_16x16x32_bf16(kf1, qfrag[qf][1], acc, 0, 0, 0);
                half4 pb;
                #pragma unroll
                for (int r = 0; r < 4; ++r) {
                    float p = __builtin_amdgcn_exp2f(acc[r] - 12.0f);
                    l_lane[qf] += p;
                    pb[r] = (_Float16)p;
                }
                #pragma unroll
                for (int dt = 0; dt < 4; ++dt)
                    Oacc[qf][dt] = __builtin_amdgcn_mfma_f32_16x16x16f16(va[dt], pb, Oacc[qf][dt], 0, 0, 0);
            }
        }
    }

    #pragma unroll
    for (int qf = 0; qf < 4; ++qf) {
        l_lane[qf] += __shfl_xor(l_lane[qf], 16, 64);
        l_lane[qf] += __shfl_xor(l_lane[qf], 32, 64);
        if (quad == 0) pl_sp[(size_t)bh*S_ + q0 + qf*16 + l16] = l_lane[qf];
    }
    #pragma unroll
    for (int qf = 0; qf < 4; ++qf) {
        const int s = q0 + qf*16 + l16;
        #pragma unroll
        for (int dt = 0; dt < 4; ++dt) {
            short4v o;
            #pragma unroll
            for (int r = 0; r < 4; ++r) o[r] = f2h(Oacc[qf][dt][r]);
            *(short4v*)(po_sp + (((size_t)b*S_ + s)*H_ + h)*HD_ + dt*16 + quad*4) = o;
        }
    }
}

extern "C" void kernel_launch(void* const* d_in, const int* in_sizes, int n_in,
                              void* d_out, int out_size, void* d_ws, size_t ws_size,
                              hipStream_t stream)
{
    (void)in_sizes; (void)n_in; (void)out_size; (void)ws_size;
    const float* x        = (const float*)d_in[0];
    const float* wq       = (const float*)d_in[1];
    const float* wk       = (const float*)d_in[2];
    const float* wv       = (const float*)d_in[3];
    const float* wo       = (const float*)d_in[4];
    const float* q_scale  = (const float*)d_in[5];
    const float* k_scale  = (const float*)d_in[6];
    const float* rope_cos = (const float*)d_in[7];
    const float* rope_sin = (const float*)d_in[8];
    float* out = (float*)d_out;
    short* ws  = (short*)d_ws;

    short* qbh   = ws;                 // 4M shorts
    short* kbh   = ws + 4194304;
    short* vt    = ws + 8388608;
    short* xb    = ws + 16777216;
    short* wqkvb = ws + 20971520;      // 3M shorts
    short* wob   = ws + 24117248;      // 1M shorts
    short* po    = ws + 25165824;      // 2 x 4M shorts (f16)
    float* pl    = (float*)(ws + 33554432);  // 2 x 64K floats

    convert_bf16<<<dim3(8192), 256, 0, stream>>>(x, wq, wk, wv, wo, xb, wqkvb, wob);
    gemm_qkv<<<dim3(M_/128, 24), 256, 0, stream>>>(xb, wqkvb, qbh, kbh, vt,
                                                   q_scale, k_scale, rope_cos, rope_sin);
    flash_mfma<<<dim3((S_/256)*B_*H_*SPLIT_), 256, 0, stream>>>(qbh, kbh, vt, po, pl);
    gemm_out<<<dim3(M_/64, D_/128), 256, 0, stream>>>(po, pl, wob, out);
}

// Round 16
// 191.665 us; speedup vs baseline: 1.0631x; 1.0111x over previous
//
#include <hip/hip_runtime.h>
#include <hip/hip_bf16.h>

// RoPEAttention B=2 S=2048 D=1024 H=16 HD=64, fp32 in/out.
// FINAL (R25): byte-exact lock-in of the measured-best build (193.8us, R15;
//      reproduced 195.3/194.1/193.8 across 4 builds). Session 210.0 -> 193.8.
//      Wins: gemm_qkv reg-staged dbuf (R20: hipcc serializes gld16 dbuf on
//      LDS-DMA alias ambiguity; precise reg deps fix it, 71->~50us),
//      gemm_out reg-staged dbuf (R21), flash Q-block 256 (R16).
//      Falsified on flash (latency-bound, MFMA 37/VALU 44/HBM 8, 2 blk/CU):
//      setprio(-6%), PV K=32(-5%), direct-L2(-228%), LDS dbuf 2x (VGPR
//      pressure: Oacc64+qfrag32 leaves no headroom), SPLIT_4 (codegen coupling).
// ws (shorts): qbh[0,4M) kbh[4M,8M) vt[8M,12M) xb[16M,20M)
//              wqkvb[20M,23M) wob[23M,24M) po[24M,32M) pl(fp32) after.

#define B_ 2
#define S_ 2048
#define D_ 1024
#define H_ 16
#define HD_ 64
#define M_ (B_*S_)
#define SPLIT_ 2
#define KSPAN_ (S_/SPLIT_)    // 1024 keys per split

typedef __attribute__((ext_vector_type(8))) short short8;
typedef __attribute__((ext_vector_type(4))) short short4v;
typedef __attribute__((ext_vector_type(4))) float f32x4;
typedef __attribute__((ext_vector_type(4))) _Float16 half4;
typedef __attribute__((ext_vector_type(8))) _Float16 half8;

static __device__ __forceinline__ short f2bf(float f) {
    __hip_bfloat16 h = __float2bfloat16(f);
    return *reinterpret_cast<short*>(&h);
}
static __device__ __forceinline__ short f2h(float f) {
    _Float16 h = (_Float16)f;
    return *reinterpret_cast<short*>(&h);
}

typedef __attribute__((address_space(1))) const unsigned int gu32_t;
typedef __attribute__((address_space(3))) unsigned int lu32_t;
static __device__ __forceinline__ void gld16(const short* g, short* l) {
    __builtin_amdgcn_global_load_lds((gu32_t*)g, (lu32_t*)l, 16, 0, 0);
}

// ---------------- fp32 -> bf16 convert: x, wq|wk|wv (concat), wo ----------------
__global__ __launch_bounds__(256)
void convert_bf16(const float* __restrict__ x,
                  const float* __restrict__ wq, const float* __restrict__ wk,
                  const float* __restrict__ wv, const float* __restrict__ wo,
                  short* __restrict__ xb, short* __restrict__ wqkvb, short* __restrict__ wob)
{
    const size_t t4 = ((size_t)blockIdx.x * 256 + threadIdx.x) * 4;
    const float* src; short* dst; size_t off, doff;
    if (t4 < 4194304)      { src = x;  dst = xb;    off = t4;           doff = t4; }
    else if (t4 < 5242880) { src = wq; dst = wqkvb; off = t4 - 4194304; doff = t4 - 4194304; }
    else if (t4 < 6291456) { src = wk; dst = wqkvb; off = t4 - 5242880; doff = t4 - 4194304; }
    else if (t4 < 7340032) { src = wv; dst = wqkvb; off = t4 - 6291456; doff = t4 - 4194304; }
    else                   { src = wo; dst = wob;   off = t4 - 7340032; doff = t4 - 7340032; }
    float4 v = *(const float4*)(src + off);
    short4v s = { f2bf(v.x), f2bf(v.y), f2bf(v.z), f2bf(v.w) };
    *(short4v*)(dst + doff) = s;
}

// ---------------- bf16 MFMA GEMM NT 128x128, BK=64 XOR-swizzled, reg-staged dbuf ----------------
// Epilogue: which==0/1 -> fused RMSNorm+RoPE -> Qb/Kb bf16 [B,H,S,HD]
//           which==2   -> Vt f16 [B,H,HD,S]
__global__ __launch_bounds__(256)
void gemm_qkv(const short* __restrict__ A, const short* __restrict__ Bw,
              short* __restrict__ Qb, short* __restrict__ Kb, short* __restrict__ Vt,
              const float* __restrict__ q_scale, const float* __restrict__ k_scale,
              const float* __restrict__ rope_cos, const float* __restrict__ rope_sin)
{
    __shared__ __align__(16) short As[2][128*64];   // 2 x 16KB
    __shared__ __align__(16) short Bs[2][128*64];   // 2 x 16KB  (total 64KB)
    const int tid = threadIdx.x;
    const int w = tid >> 6, lane = tid & 63, quad = lane >> 4, l16 = lane & 15;
    const int wr = w >> 1, wc = w & 1;
    const int bm0 = blockIdx.x * 128, bn0 = blockIdx.y * 128;

    const int row_ = tid >> 3;
    const int kslot = tid & 7;
    const short* gA[4]; const short* gB[4];
    int wo_[4];
    #pragma unroll
    for (int j = 0; j < 4; ++j) {
        const int row = j*32 + row_;
        const int kch = kslot ^ (row & 7);
        gA[j] = A  + (size_t)(bm0 + row) * 1024 + kch*8;
        gB[j] = Bw + (size_t)(bn0 + row) * 1024 + kch*8;
        wo_[j] = row*64 + kslot*8;       // == j*2048 + w*512 + lane*8
    }

    f32x4 acc[4][4];
    #pragma unroll
    for (int i = 0; i < 4; ++i)
        #pragma unroll
        for (int j = 0; j < 4; ++j) acc[i][j] = (f32x4){0.f,0.f,0.f,0.f};

    // prologue: tile0 -> regs -> buf0; tile1 -> regs; barrier
    short8 rA[4], rB[4];
    #pragma unroll
    for (int j = 0; j < 4; ++j) { rA[j] = *(const short8*)gA[j]; rB[j] = *(const short8*)gB[j]; }
    #pragma unroll
    for (int j = 0; j < 4; ++j) {
        *(short8*)(&As[0][wo_[j]]) = rA[j];
        *(short8*)(&Bs[0][wo_[j]]) = rB[j];
    }
    #pragma unroll
    for (int j = 0; j < 4; ++j) { rA[j] = *(const short8*)(gA[j] + 64); rB[j] = *(const short8*)(gB[j] + 64); }
    asm volatile("s_waitcnt lgkmcnt(0)" ::: "memory");
    __builtin_amdgcn_s_barrier();
    __builtin_amdgcn_sched_barrier(0);

    int cur = 0;
    for (int t = 0; t < 16; ++t) {
        // compute tile t from buf[cur]
        short8 af[2][4], bfr[2][4];
        #pragma unroll
        for (int ph = 0; ph < 2; ++ph)
            #pragma unroll
            for (int i = 0; i < 4; ++i) {
                const int ra = wr*64 + i*16 + l16;
                af[ph][i]  = *(const short8*)(&As[cur][ra*64 + (((ph*4 + quad) ^ (ra & 7)) << 3)]);
                const int rb = wc*64 + i*16 + l16;
                bfr[ph][i] = *(const short8*)(&Bs[cur][rb*64 + (((ph*4 + quad) ^ (rb & 7)) << 3)]);
            }
        #pragma unroll
        for (int ph = 0; ph < 2; ++ph)
            #pragma unroll
            for (int i = 0; i < 4; ++i)
                #pragma unroll
                for (int j = 0; j < 4; ++j)
                    acc[i][j] = __builtin_amdgcn_mfma_f32_16x16x32_bf16(af[ph][i], bfr[ph][j], acc[i][j], 0, 0, 0);

        if (t < 15) {
            // commit tile t+1 (in regs since last iter) to the other buffer
            #pragma unroll
            for (int j = 0; j < 4; ++j) {
                *(short8*)(&As[cur ^ 1][wo_[j]]) = rA[j];
                *(short8*)(&Bs[cur ^ 1][wo_[j]]) = rB[j];
            }
            // issue tile t+2 loads (stay in flight across the barrier: no vmcnt drain)
            if (t < 14) {
                const int k0 = (t + 2) * 64;
                #pragma unroll
                for (int j = 0; j < 4; ++j) {
                    rA[j] = *(const short8*)(gA[j] + k0);
                    rB[j] = *(const short8*)(gB[j] + k0);
                }
            }
            asm volatile("s_waitcnt lgkmcnt(0)" ::: "memory");
            __builtin_amdgcn_s_barrier();
            __builtin_amdgcn_sched_barrier(0);
            cur ^= 1;
        }
    }

    const int nbase = bn0 + wc*64;
    const int which = nbase >> 10;
    const int h     = (nbase & 1023) >> 6;

    if (which < 2) {
        const float* sc = which ? k_scale : q_scale;
        short* dst      = which ? Kb : Qb;
        const float fold = which ? 1.0f : 0.18033688011112042f;  // q: (1/8)*log2(e)
        float scv[4];
        #pragma unroll
        for (int j = 0; j < 4; ++j) scv[j] = sc[j*16 + l16];
        #pragma unroll
        for (int i = 0; i < 4; ++i) {
            #pragma unroll
            for (int r = 0; r < 4; ++r) {
                const int m = bm0 + wr*64 + i*16 + quad*4 + r;
                const int b = m >> 11, s = m & (S_-1);
                float ss = 0.f;
                #pragma unroll
                for (int j = 0; j < 4; ++j) ss += acc[i][j][r] * acc[i][j][r];
                #pragma unroll
                for (int msk = 1; msk <= 8; msk <<= 1) ss += __shfl_xor(ss, msk, 64);
                const float rn = rsqrtf(ss * (1.0f/64.0f) + 1e-6f);
                #pragma unroll
                for (int j = 0; j < 4; ++j) {
                    const int hd = j*16 + l16;
                    const float nv = acc[i][j][r] * rn * scv[j];
                    const float c  = rope_cos[s*32 + (hd >> 1)];
                    const float sn = rope_sin[s*32 + (hd >> 1)];
                    const float partner = __shfl_xor(nv, 1, 64);
                    const float o = (hd & 1) ? (partner * sn + nv * c) : (nv * c - partner * sn);
                    dst[(((size_t)b*H_ + h)*S_ + s)*HD_ + hd] = f2bf(o * fold);
                }
            }
        }
    } else {
        #pragma unroll
        for (int i = 0; i < 4; ++i)
            #pragma unroll
            for (int r = 0; r < 4; ++r) {
                const int m = bm0 + wr*64 + i*16 + quad*4 + r;
                const int b = m >> 11, s = m & (S_-1);
                #pragma unroll
                for (int j = 0; j < 4; ++j) {
                    const int hd = j*16 + l16;
                    Vt[(((size_t)b*H_ + h)*HD_ + hd)*S_ + s] = f2h(acc[i][j][r]);
                }
            }
    }
}

// ---------------- out-proj GEMM 64x128, BK=64 XOR-swizzled, reg-staged dbuf ----------------
__global__ __launch_bounds__(256)
void gemm_out(const short* __restrict__ po, const float* __restrict__ pl,
              const short* __restrict__ Bw, float* __restrict__ C)
{
    __shared__ __align__(16) short As[2][64*64];    // 2 x 8KB
    __shared__ __align__(16) short Bs[2][128*64];   // 2 x 16KB (total 48KB)
    const int tid = threadIdx.x;
    const int w = tid >> 6, lane = tid & 63, quad = lane >> 4, l16 = lane & 15;
    const int bm0 = blockIdx.x * 64, bn0 = blockIdx.y * 128;

    // B reg-staging (same slot math as gemm_qkv)
    const int row_ = tid >> 3;
    const int kslot = tid & 7;
    const short* gB[4];
    int woB[4];
    #pragma unroll
    for (int j = 0; j < 4; ++j) {
        const int row = j*32 + row_;
        const int kch = kslot ^ (row & 7);
        gB[j] = Bw + (size_t)(bn0 + row) * 1024 + kch*8;
        woB[j] = row*64 + kslot*8;
    }

    // A production: thread -> row srow, chunks ch0, ch0+1 (8 shorts each)
    const int srow = tid >> 2;          // 0..63
    const int ch0  = (tid & 3) * 2;     // 0,2,4,6
    const int m = bm0 + srow;
    const int b = m >> 11, s = m & (S_-1);
    const short* p0 = po +            (size_t)m * 1024;
    const short* p1 = po + 4194304 + (size_t)m * 1024;

    float inv[16];
    #pragma unroll
    for (int h = 0; h < 16; ++h)
        inv[h] = 1.0f / (pl[((size_t)(b*16 + h))*S_ + s] + pl[65536 + ((size_t)(b*16 + h))*S_ + s]);

    f32x4 acc[4][2];
    #pragma unroll
    for (int i = 0; i < 4; ++i) {
        acc[i][0] = (f32x4){0.f,0.f,0.f,0.f};
        acc[i][1] = (f32x4){0.f,0.f,0.f,0.f};
    }

    // ---- prologue: tile0 -> regs -> buf0; tile1 -> regs; barrier ----
    short8 rB[4];
    half8 d00, d01, d10, d11;
    #pragma unroll
    for (int j = 0; j < 4; ++j) rB[j] = *(const short8*)gB[j];
    d00 = *(const half8*)(p0 + ch0*8);
    d01 = *(const half8*)(p1 + ch0*8);
    d10 = *(const half8*)(p0 + ch0*8 + 8);
    d11 = *(const half8*)(p1 + ch0*8 + 8);
    {
        const float invh = inv[0];
        short8 a0, a1;
        #pragma unroll
        for (int j = 0; j < 8; ++j) {
            a0[j] = f2bf(((float)d00[j] + (float)d01[j]) * invh);
            a1[j] = f2bf(((float)d10[j] + (float)d11[j]) * invh);
        }
        *(short8*)(&As[0][srow*64 + (((ch0    ) ^ (srow & 7)) << 3)]) = a0;
        *(short8*)(&As[0][srow*64 + (((ch0 + 1) ^ (srow & 7)) << 3)]) = a1;
        #pragma unroll
        for (int j = 0; j < 4; ++j)
            *(short8*)(&Bs[0][woB[j]]) = rB[j];
    }
    #pragma unroll
    for (int j = 0; j < 4; ++j) rB[j] = *(const short8*)(gB[j] + 64);
    d00 = *(const half8*)(p0 + 64 + ch0*8);
    d01 = *(const half8*)(p1 + 64 + ch0*8);
    d10 = *(const half8*)(p0 + 64 + ch0*8 + 8);
    d11 = *(const half8*)(p1 + 64 + ch0*8 + 8);
    asm volatile("s_waitcnt lgkmcnt(0)" ::: "memory");
    __builtin_amdgcn_s_barrier();
    __builtin_amdgcn_sched_barrier(0);

    int cur = 0;
    for (int t = 0; t < 16; ++t) {
        // compute tile t from buf[cur]
        #pragma unroll
        for (int ph = 0; ph < 2; ++ph) {
            short8 af[4], bfr[2];
            #pragma unroll
            for (int i = 0; i < 4; ++i) {
                const int ra = i*16 + l16;
                af[i] = *(const short8*)(&As[cur][ra*64 + (((ph*4 + quad) ^ (ra & 7)) << 3)]);
            }
            #pragma unroll
            for (int j = 0; j < 2; ++j) {
                const int rb = w*32 + j*16 + l16;
                bfr[j] = *(const short8*)(&Bs[cur][rb*64 + (((ph*4 + quad) ^ (rb & 7)) << 3)]);
            }
            #pragma unroll
            for (int i = 0; i < 4; ++i)
                #pragma unroll
                for (int j = 0; j < 2; ++j)
                    acc[i][j] = __builtin_amdgcn_mfma_f32_16x16x32_bf16(af[i], bfr[j], acc[i][j], 0, 0, 0);
        }

        if (t < 15) {
            // commit tile t+1 (regs) to the other buffer
            const float invh = inv[t + 1];
            short8 a0, a1;
            #pragma unroll
            for (int j = 0; j < 8; ++j) {
                a0[j] = f2bf(((float)d00[j] + (float)d01[j]) * invh);
                a1[j] = f2bf(((float)d10[j] + (float)d11[j]) * invh);
            }
            *(short8*)(&As[cur ^ 1][srow*64 + (((ch0    ) ^ (srow & 7)) << 3)]) = a0;
            *(short8*)(&As[cur ^ 1][srow*64 + (((ch0 + 1) ^ (srow & 7)) << 3)]) = a1;
            #pragma unroll
            for (int j = 0; j < 4; ++j)
                *(short8*)(&Bs[cur ^ 1][woB[j]]) = rB[j];
            // issue tile t+2 loads (no vmcnt drain; stay in flight across barrier)
            if (t < 14) {
                const int k0 = (t + 2) * 64;
                #pragma unroll
                for (int j = 0; j < 4; ++j) rB[j] = *(const short8*)(gB[j] + k0);
                d00 = *(const half8*)(p0 + k0 + ch0*8);
                d01 = *(const half8*)(p1 + k0 + ch0*8);
                d10 = *(const half8*)(p0 + k0 + ch0*8 + 8);
                d11 = *(const half8*)(p1 + k0 + ch0*8 + 8);
            }
            asm volatile("s_waitcnt lgkmcnt(0)" ::: "memory");
            __builtin_amdgcn_s_barrier();
            __builtin_amdgcn_sched_barrier(0);
            cur ^= 1;
        }
    }

    #pragma unroll
    for (int i = 0; i < 4; ++i)
        #pragma unroll
        for (int r = 0; r < 4; ++r) {
            const int mm = bm0 + i*16 + quad*4 + r;
            #pragma unroll
            for (int j = 0; j < 2; ++j) {
                const int n = bn0 + w*32 + j*16 + l16;
                C[(size_t)mm*1024 + n] = acc[i][j][r];
            }
        }
}

// ---------------- MFMA flash attention partial, split-K=2, XCD-swizzled, Q-block 256 ----------------
__global__ __launch_bounds__(256)
void flash_mfma(const short* __restrict__ qb, const short* __restrict__ kb,
                const short* __restrict__ vt, short* __restrict__ po, float* __restrict__ pl)
{
    __shared__ __align__(16) short Ks[64*64];
    __shared__ __align__(16) short Vs[64*64];   // f16 bits, [d][key] swizzled

    const int id   = blockIdx.x;
    const int xcd  = id & 7;
    const int rest = id >> 3;
    const int qblk = rest & 7;                // 8 q-blocks of 256
    const int g    = (rest >> 3) * 8 + xcd;   // (bh,sp) group 0..63
    const int bh   = g >> 1;
    const int sp   = g & 1;

    const int tid  = threadIdx.x;
    const int wv   = tid >> 6;
    const int lane = tid & 63;
    const int quad = lane >> 4;
    const int l16  = lane & 15;
    const int b    = bh >> 4, h = bh & (H_-1);
    const int q0   = qblk * 256 + wv * 64;    // 64 q-rows per wave
    const int kt0  = sp * KSPAN_;
    const size_t hbase = (size_t)bh * S_ * HD_;
    const size_t vbase = (size_t)bh * HD_ * S_;
    short* po_sp = po + (size_t)sp * 4194304;
    float* pl_sp = pl + (size_t)sp * 65536;

    const int c0r = tid >> 3,       c0c = tid & 7;
    const int c1r = (tid+256) >> 3, c1c = (tid+256) & 7;

    short8 qfrag[4][2];
    #pragma unroll
    for (int qf = 0; qf < 4; ++qf)
        #pragma unroll
        for (int c = 0; c < 2; ++c)
            qfrag[qf][c] = *(const short8*)(qb + hbase + (size_t)(q0 + qf*16 + l16)*HD_ + c*32 + quad*8);

    f32x4 Oacc[4][4];
    #pragma unroll
    for (int qf = 0; qf < 4; ++qf)
        #pragma unroll
        for (int dt = 0; dt < 4; ++dt) Oacc[qf][dt] = (f32x4){0.f,0.f,0.f,0.f};
    float l_lane[4] = {0.f, 0.f, 0.f, 0.f};

    short8 rk0 = *(const short8*)(kb + hbase + (size_t)(kt0 + c0r)*HD_ + c0c*8);
    short8 rk1 = *(const short8*)(kb + hbase + (size_t)(kt0 + c1r)*HD_ + c1c*8);
    short8 rv0 = *(const short8*)(vt + vbase + (size_t)c0r*S_ + kt0 + c0c*8);
    short8 rv1 = *(const short8*)(vt + vbase + (size_t)c1r*S_ + kt0 + c1c*8);

    #pragma unroll 1
    for (int t = 0; t < KSPAN_/64; ++t) {
        __syncthreads();
        *(short8*)(Ks + c0r*64 + ((c0c ^ (c0r & 7)) << 3)) = rk0;
        *(short8*)(Ks + c1r*64 + ((c1c ^ (c1r & 7)) << 3)) = rk1;
        *(short8*)(Vs + c0r*64 + ((c0c ^ (c0r & 7)) << 3)) = rv0;
        *(short8*)(Vs + c1r*64 + ((c1c ^ (c1r & 7)) << 3)) = rv1;
        __syncthreads();
        if (t < KSPAN_/64 - 1) {
            const int ktn = kt0 + (t+1)*64;
            rk0 = *(const short8*)(kb + hbase + (size_t)(ktn + c0r)*HD_ + c0c*8);
            rk1 = *(const short8*)(kb + hbase + (size_t)(ktn + c1r)*HD_ + c1c*8);
            rv0 = *(const short8*)(vt + vbase + (size_t)c0r*S_ + ktn + c0c*8);
            rv1 = *(const short8*)(vt + vbase + (size_t)c1r*S_ + ktn + c1c*8);
        }

        #pragma unroll
        for (int st = 0; st < 4; ++st) {
            short8 kf0 = *(const short8*)(Ks + (st*16 + l16)*64 + (((quad    ) ^ (l16 & 7)) << 3));
            short8 kf1 = *(const short8*)(Ks + (st*16 + l16)*64 + (((4 + quad) ^ (l16 & 7)) << 3));
            const int ch16 = st*2 + (quad >> 1);
            const int sw   = ((ch16 ^ (l16 & 7)) << 3) + (quad & 1)*4;
            half4 va[4];
            #pragma unroll
            for (int dt = 0; dt < 4; ++dt)
                va[dt] = *(const half4*)(Vs + (dt*16 + l16)*64 + sw);
            #pragma unroll
            for (int qf = 0; qf < 4; ++qf) {
                f32x4 acc = (f32x4){0.f,0.f,0.f,0.f};
                acc = __builtin_amdgcn_mfma_f32_16x16x32_bf16(kf0, qfrag[qf][0], acc, 0, 0, 0);
                acc = __builtin_amdgcn_mfma_f32_16x16x32_bf16(kf1, qfrag[qf][1], acc, 0, 0, 0);
                half4 pb;
                #pragma unroll
                for (int r = 0; r < 4; ++r) {
                    float p = __builtin_amdgcn_exp2f(acc[r] - 12.0f);
                    l_lane[qf] += p;
                    pb[r] = (_Float16)p;
                }
                #pragma unroll
                for (int dt = 0; dt < 4; ++dt)
                    Oacc[qf][dt] = __builtin_amdgcn_mfma_f32_16x16x16f16(va[dt], pb, Oacc[qf][dt], 0, 0, 0);
            }
        }
    }

    #pragma unroll
    for (int qf = 0; qf < 4; ++qf) {
        l_lane[qf] += __shfl_xor(l_lane[qf], 16, 64);
        l_lane[qf] += __shfl_xor(l_lane[qf], 32, 64);
        if (quad == 0) pl_sp[(size_t)bh*S_ + q0 + qf*16 + l16] = l_lane[qf];
    }
    #pragma unroll
    for (int qf = 0; qf < 4; ++qf) {
        const int s = q0 + qf*16 + l16;
        #pragma unroll
        for (int dt = 0; dt < 4; ++dt) {
            short4v o;
            #pragma unroll
            for (int r = 0; r < 4; ++r) o[r] = f2h(Oacc[qf][dt][r]);
            *(short4v*)(po_sp + (((size_t)b*S_ + s)*H_ + h)*HD_ + dt*16 + quad*4) = o;
        }
    }
}

extern "C" void kernel_launch(void* const* d_in, const int* in_sizes, int n_in,
                              void* d_out, int out_size, void* d_ws, size_t ws_size,
                              hipStream_t stream)
{
    (void)in_sizes; (void)n_in; (void)out_size; (void)ws_size;
    const float* x        = (const float*)d_in[0];
    const float* wq       = (const float*)d_in[1];
    const float* wk       = (const float*)d_in[2];
    const float* wv       = (const float*)d_in[3];
    const float* wo       = (const float*)d_in[4];
    const float* q_scale  = (const float*)d_in[5];
    const float* k_scale  = (const float*)d_in[6];
    const float* rope_cos = (const float*)d_in[7];
    const float* rope_sin = (const float*)d_in[8];
    float* out = (float*)d_out;
    short* ws  = (short*)d_ws;

    short* qbh   = ws;                 // 4M shorts
    short* kbh   = ws + 4194304;
    short* vt    = ws + 8388608;
    short* xb    = ws + 16777216;
    short* wqkvb = ws + 20971520;      // 3M shorts
    short* wob   = ws + 24117248;      // 1M shorts
    short* po    = ws + 25165824;      // 2 x 4M shorts (f16)
    float* pl    = (float*)(ws + 33554432);  // 2 x 64K floats

    convert_bf16<<<dim3(8192), 256, 0, stream>>>(x, wq, wk, wv, wo, xb, wqkvb, wob);
    gemm_qkv<<<dim3(M_/128, 24), 256, 0, stream>>>(xb, wqkvb, qbh, kbh, vt,
                                                   q_scale, k_scale, rope_cos, rope_sin);
    flash_mfma<<<dim3((S_/256)*B_*H_*SPLIT_), 256, 0, stream>>>(qbh, kbh, vt, po, pl);
    gemm_out<<<dim3(M_/64, D_/128), 256, 0, stream>>>(po, pl, wob, out);
}